// Round 1
// baseline (53533.856 us; speedup 1.0000x reference)
//
#include <hip/hip_runtime.h>
#include <hip/hip_bf16.h>

#define TT 16384       // B*L tokens
#define LSEQ 2048
#define BB 8
#define DMOD 128
#define II 256
#define NN 16

// ---------------- embed ----------------
__global__ __launch_bounds__(256) void embed_kernel(const int* __restrict__ x,
                                                    const float* __restrict__ emb,
                                                    float* __restrict__ h) {
  int idx = blockIdx.x * 256 + threadIdx.x;   // T*128 total
  int t = idx >> 7;
  int d = idx & 127;
  h[idx] = emb[(size_t)x[t] * DMOD + d];
}

// ---------------- rmsnorm ----------------
__global__ __launch_bounds__(256) void rmsnorm_kernel(const float* __restrict__ hin,
                                                      const float* __restrict__ w,
                                                      float* __restrict__ hout) {
  int row = blockIdx.x * 4 + (threadIdx.x >> 6);
  int lane = threadIdx.x & 63;
  const float* r = hin + (size_t)row * DMOD;
  float2 v = *(const float2*)&r[lane * 2];
  float ss = v.x * v.x + v.y * v.y;
  #pragma unroll
  for (int m = 1; m < 64; m <<= 1) ss += __shfl_xor(ss, m);
  float rstd = rsqrtf(ss * (1.0f / 128.0f) + 1e-5f);
  float2 wv = *(const float2*)&w[lane * 2];
  float2 o;
  o.x = v.x * rstd * wv.x;
  o.y = v.y * rstd * wv.y;
  *(float2*)&hout[(size_t)row * DMOD + lane * 2] = o;
}

// ---------------- generic f32 tiled GEMM: C[M,Nc] = A[M,Kc] @ W[Nc,Kc]^T ----------------
// EPI 0: store   EPI 1: C += (residual)   EPI 2: store + bias
template <int EPI>
__global__ __launch_bounds__(256) void gemm_kernel(const float* __restrict__ A,
                                                   const float* __restrict__ W,
                                                   float* __restrict__ C,
                                                   const float* __restrict__ bias,
                                                   int Nc, int Kc) {
  __shared__ float As[64 * 68];
  __shared__ float Bs[64 * 76];
  int tid = threadIdx.x;
  int tx = tid & 15, ty = tid >> 4;
  int row0 = blockIdx.x << 6, col0 = blockIdx.y << 6;
  float acc[4][4] = {};
  for (int k0 = 0; k0 < Kc; k0 += 64) {
    #pragma unroll
    for (int it = 0; it < 4; ++it) {
      int fidx = (it << 8) + tid;          // 0..1023
      int m = fidx >> 4;                   // 0..63
      int kv = (fidx & 15) << 2;           // 0..60 step 4
      *(float4*)&As[m * 68 + kv] = *(const float4*)&A[(size_t)(row0 + m) * Kc + k0 + kv];
      float4 bvv = make_float4(0.f, 0.f, 0.f, 0.f);
      if (col0 + m < Nc) bvv = *(const float4*)&W[(size_t)(col0 + m) * Kc + k0 + kv];
      *(float4*)&Bs[m * 76 + kv] = bvv;
    }
    __syncthreads();
    #pragma unroll
    for (int kk = 0; kk < 16; ++kk) {
      float4 a[4], bq[4];
      #pragma unroll
      for (int u = 0; u < 4; ++u) a[u] = *(float4*)&As[(ty * 4 + u) * 68 + kk * 4];
      #pragma unroll
      for (int u = 0; u < 4; ++u) bq[u] = *(float4*)&Bs[(tx * 4 + u) * 76 + kk * 4];
      #pragma unroll
      for (int iy = 0; iy < 4; ++iy)
        #pragma unroll
        for (int jx = 0; jx < 4; ++jx) {
          acc[iy][jx] = fmaf(a[iy].x, bq[jx].x, acc[iy][jx]);
          acc[iy][jx] = fmaf(a[iy].y, bq[jx].y, acc[iy][jx]);
          acc[iy][jx] = fmaf(a[iy].z, bq[jx].z, acc[iy][jx]);
          acc[iy][jx] = fmaf(a[iy].w, bq[jx].w, acc[iy][jx]);
        }
    }
    __syncthreads();
  }
  int cb = col0 + tx * 4;
  if (cb >= Nc) return;   // only trips for Nc=40 tile
  #pragma unroll
  for (int iy = 0; iy < 4; ++iy) {
    int r = row0 + ty * 4 + iy;
    float4 v = make_float4(acc[iy][0], acc[iy][1], acc[iy][2], acc[iy][3]);
    size_t off = (size_t)r * Nc + cb;
    if (EPI == 1) {
      float4 old = *(float4*)&C[off];
      v.x += old.x; v.y += old.y; v.z += old.z; v.w += old.w;
    } else if (EPI == 2) {
      float4 bb = *(const float4*)&bias[cb];
      v.x += bb.x; v.y += bb.y; v.z += bb.z; v.w += bb.w;
    }
    *(float4*)&C[off] = v;
  }
}

// ---------------- causal depthwise conv (K=4) + bias + silu ----------------
__global__ __launch_bounds__(256) void conv_silu_kernel(const float* __restrict__ hz,
                                                        const float* __restrict__ cw,
                                                        const float* __restrict__ cb,
                                                        float* __restrict__ hs) {
  int idx = blockIdx.x * 256 + threadIdx.x;   // T*256
  int ch = idx & 255;
  int t = idx >> 8;
  int b = t >> 11;
  int l = t & (LSEQ - 1);
  float s = cb[ch];
  const float* w = cw + ch * 4;
  #pragma unroll
  for (int k = 0; k < 4; ++k) {
    int ll = l + k - 3;
    if (ll >= 0) s += hz[((size_t)(b << 11) + ll) * 512 + ch] * w[k];
  }
  hs[idx] = s / (1.0f + __expf(-s));
}

// ---------------- dt_proj (K=8) + softplus ----------------
__global__ __launch_bounds__(256) void dtproj_kernel(const float* __restrict__ xp,
                                                     const float* __restrict__ Wdt,
                                                     const float* __restrict__ bdt,
                                                     float* __restrict__ dtb) {
  int t = blockIdx.x;
  int i = threadIdx.x;
  const float* xr = xp + (size_t)t * 40;
  const float* wr = Wdt + i * 8;
  float s = bdt[i];
  #pragma unroll
  for (int r = 0; r < 8; ++r) s += xr[r] * wr[r];
  float sp = (s > 20.0f) ? s : log1pf(__expf(s));
  dtb[(size_t)t * II + i] = sp;
}

// ---------------- selective scan (sequential over L), fused y = (h·C + hs·D)·silu(gate) ----------------
__global__ __launch_bounds__(64) void scan_kernel(const float* __restrict__ dtb,
                                                  const float* __restrict__ hs,
                                                  const float* __restrict__ xp,
                                                  const float* __restrict__ A_log,
                                                  const float* __restrict__ Dp,
                                                  const float* __restrict__ hz,
                                                  float* __restrict__ y) {
  int b = blockIdx.x;
  int i = blockIdx.y * 4 + (threadIdx.x >> 4);
  int n = threadIdx.x & 15;
  float A = -__expf(A_log[i * NN + n]);
  float Dv = Dp[i];
  float state = 0.0f;
  size_t tbase = (size_t)b * LSEQ;
  for (int l = 0; l < LSEQ; ++l) {
    size_t t = tbase + l;
    float dtv = dtb[t * II + i];
    float hsv = hs[t * II + i];
    float bv = xp[t * 40 + 8 + n];
    float cv = xp[t * 40 + 24 + n];
    float dA = __expf(dtv * A);
    state = fmaf(state, dA, dtv * bv * hsv);
    float contrib = state * cv;
    contrib += __shfl_xor(contrib, 1, 16);
    contrib += __shfl_xor(contrib, 2, 16);
    contrib += __shfl_xor(contrib, 4, 16);
    contrib += __shfl_xor(contrib, 8, 16);
    if (n == 0) {
      float g = hz[t * 512 + 256 + i];
      y[t * II + i] = (contrib + hsv * Dv) * (g / (1.0f + __expf(-g)));
    }
  }
}

extern "C" void kernel_launch(void* const* d_in, const int* in_sizes, int n_in,
                              void* d_out, int out_size, void* d_ws, size_t ws_size,
                              hipStream_t stream) {
  const int* x          = (const int*)d_in[0];
  const float* embed    = (const float*)d_in[1];
  const float* in_proj_w = (const float*)d_in[2];
  const float* conv_w   = (const float*)d_in[3];
  const float* conv_b   = (const float*)d_in[4];
  const float* x_proj_w = (const float*)d_in[5];
  const float* dt_proj_w = (const float*)d_in[6];
  const float* dt_proj_b = (const float*)d_in[7];
  const float* A_log    = (const float*)d_in[8];
  const float* Dp       = (const float*)d_in[9];
  const float* out_proj_w = (const float*)d_in[10];
  const float* norm_w   = (const float*)d_in[11];
  const float* norm_f_w = (const float*)d_in[12];
  const float* head_w   = (const float*)d_in[13];
  const float* head_b   = (const float*)d_in[14];

  float* out = (float*)d_out;
  float* ws = (float*)d_ws;

  // ws scratch (19.4 MB): h, hn, xp
  float* h  = ws;                  // T*128
  float* hn = ws + 2097152;        // T*128
  float* xp = ws + 2 * 2097152;    // T*40

  // d_out used as scratch for the big per-layer buffers (dead before head GEMM):
  float* hz  = out;                          // T*512  (cols 0..255 = pre-conv hs, 256..511 = gate)
  float* hs  = out + 8388608;                // T*256
  float* dtb = out + 8388608 + 4194304;      // T*256
  float* y   = out + 8388608 + 2 * 4194304;  // T*256  (total 20.97M <= 33.55M elems)

  embed_kernel<<<8192, 256, 0, stream>>>(x, embed, h);

  for (int l = 0; l < 32; ++l) {
    rmsnorm_kernel<<<4096, 256, 0, stream>>>(h, norm_w + l * DMOD, hn);
    gemm_kernel<0><<<dim3(256, 8), 256, 0, stream>>>(hn, in_proj_w + (size_t)l * 512 * 128, hz,
                                                     nullptr, 512, 128);
    conv_silu_kernel<<<16384, 256, 0, stream>>>(hz, conv_w + l * 1024, conv_b + l * 256, hs);
    gemm_kernel<0><<<dim3(256, 1), 256, 0, stream>>>(hs, x_proj_w + (size_t)l * 40 * 256, xp,
                                                     nullptr, 40, 256);
    dtproj_kernel<<<16384, 256, 0, stream>>>(xp, dt_proj_w + l * 2048, dt_proj_b + l * 256, dtb);
    scan_kernel<<<dim3(8, 64), 64, 0, stream>>>(dtb, hs, xp, A_log + l * 4096, Dp + l * 256, hz, y);
    gemm_kernel<1><<<dim3(256, 2), 256, 0, stream>>>(y, out_proj_w + (size_t)l * 128 * 256, h,
                                                     nullptr, 128, 256);
  }

  rmsnorm_kernel<<<4096, 256, 0, stream>>>(h, norm_f_w, hn);
  gemm_kernel<2><<<dim3(256, 32), 256, 0, stream>>>(hn, head_w, out, head_b, 2048, 128);
}

// Round 2
// 8502.933 us; speedup vs baseline: 6.2959x; 6.2959x over previous
//
#include <hip/hip_runtime.h>
#include <hip/hip_bf16.h>

#define TT 16384       // B*L tokens
#define LSEQ 2048

// ---------------- embed ----------------
__global__ __launch_bounds__(256) void embed_kernel(const int* __restrict__ x,
                                                    const float* __restrict__ emb,
                                                    float* __restrict__ h) {
  int idx = blockIdx.x * 256 + threadIdx.x;   // T*128 total
  int t = idx >> 7;
  int d = idx & 127;
  h[idx] = emb[(size_t)x[t] * 128 + d];
}

// ---------------- fused rmsnorm + GEMM (K=128): C = rms(A,nw) @ W^T (+bias) ----------------
// EPI 0: store    EPI 2: store + bias
template <int EPI>
__global__ __launch_bounds__(256) void gemm_norm_kernel(const float* __restrict__ A,
                                                        const float* __restrict__ W,
                                                        const float* __restrict__ nw,
                                                        float* __restrict__ C,
                                                        const float* __restrict__ bias,
                                                        int Nc) {
  __shared__ float As[64 * 132];
  __shared__ float Bs[64 * 68];
  __shared__ float srstd[64];
  int tid = threadIdx.x;
  int tx = tid & 15, ty = tid >> 4;
  int row0 = blockIdx.x << 6, col0 = blockIdx.y << 6;
  // stage full A rows (64 x 128)
  #pragma unroll
  for (int it = 0; it < 8; ++it) {
    int fidx = it * 256 + tid;
    int m = fidx >> 5, kq = (fidx & 31) << 2;
    *(float4*)&As[m * 132 + kq] = *(const float4*)&A[(size_t)(row0 + m) * 128 + kq];
  }
  __syncthreads();
  // row sum of squares: 4 threads per row
  {
    int r = tid >> 2, p = tid & 3;
    const float* rp = &As[r * 132 + p * 32];
    float s = 0.f;
    #pragma unroll
    for (int j = 0; j < 32; ++j) { float v = rp[j]; s = fmaf(v, v, s); }
    s += __shfl_xor(s, 1);
    s += __shfl_xor(s, 2);
    if (p == 0) srstd[r] = rsqrtf(s * (1.0f / 128.0f) + 1e-5f);
  }
  __syncthreads();
  // rescale staged A by rstd * nw
  #pragma unroll
  for (int it = 0; it < 8; ++it) {
    int fidx = it * 256 + tid;
    int m = fidx >> 5, kq = (fidx & 31) << 2;
    float4 v = *(float4*)&As[m * 132 + kq];
    float4 w = *(const float4*)&nw[kq];
    float rs = srstd[m];
    v.x *= rs * w.x; v.y *= rs * w.y; v.z *= rs * w.z; v.w *= rs * w.w;
    *(float4*)&As[m * 132 + kq] = v;
  }
  float acc[4][4] = {};
  for (int kc = 0; kc < 2; ++kc) {
    __syncthreads();
    #pragma unroll
    for (int it = 0; it < 4; ++it) {
      int fidx = it * 256 + tid;
      int m = fidx >> 4, kq = (fidx & 15) << 2;
      *(float4*)&Bs[m * 68 + kq] = *(const float4*)&W[(size_t)(col0 + m) * 128 + kc * 64 + kq];
    }
    __syncthreads();
    #pragma unroll
    for (int kk = 0; kk < 16; ++kk) {
      float4 a[4], b[4];
      #pragma unroll
      for (int u = 0; u < 4; ++u) a[u] = *(float4*)&As[(ty + 16 * u) * 132 + kc * 64 + kk * 4];
      #pragma unroll
      for (int v = 0; v < 4; ++v) b[v] = *(float4*)&Bs[(tx + 16 * v) * 68 + kk * 4];
      #pragma unroll
      for (int u = 0; u < 4; ++u)
        #pragma unroll
        for (int v = 0; v < 4; ++v) {
          acc[u][v] = fmaf(a[u].x, b[v].x, acc[u][v]);
          acc[u][v] = fmaf(a[u].y, b[v].y, acc[u][v]);
          acc[u][v] = fmaf(a[u].z, b[v].z, acc[u][v]);
          acc[u][v] = fmaf(a[u].w, b[v].w, acc[u][v]);
        }
    }
  }
  #pragma unroll
  for (int u = 0; u < 4; ++u) {
    int r = row0 + ty + 16 * u;
    #pragma unroll
    for (int v = 0; v < 4; ++v) {
      int c = col0 + tx + 16 * v;
      float val = acc[u][v];
      if (EPI == 2) val += bias[c];
      C[(size_t)r * Nc + c] = val;
    }
  }
}

// ---------------- generic f32 GEMM (K multiple of 64): C = A @ W^T ----------------
// EPI 0: store    EPI 1: C += (residual accumulate)
template <int EPI>
__global__ __launch_bounds__(256) void gemm_k_kernel(const float* __restrict__ A,
                                                     const float* __restrict__ W,
                                                     float* __restrict__ C,
                                                     int Nc, int Kc) {
  __shared__ float As[64 * 68];
  __shared__ float Bs[64 * 68];
  int tid = threadIdx.x;
  int tx = tid & 15, ty = tid >> 4;
  int row0 = blockIdx.x << 6, col0 = blockIdx.y << 6;
  float acc[4][4] = {};
  for (int k0 = 0; k0 < Kc; k0 += 64) {
    #pragma unroll
    for (int it = 0; it < 4; ++it) {
      int fidx = it * 256 + tid;
      int m = fidx >> 4, kq = (fidx & 15) << 2;
      *(float4*)&As[m * 68 + kq] = *(const float4*)&A[(size_t)(row0 + m) * Kc + k0 + kq];
      float4 bv = make_float4(0.f, 0.f, 0.f, 0.f);
      if (col0 + m < Nc) bv = *(const float4*)&W[(size_t)(col0 + m) * Kc + k0 + kq];
      *(float4*)&Bs[m * 68 + kq] = bv;
    }
    __syncthreads();
    #pragma unroll
    for (int kk = 0; kk < 16; ++kk) {
      float4 a[4], b[4];
      #pragma unroll
      for (int u = 0; u < 4; ++u) a[u] = *(float4*)&As[(ty + 16 * u) * 68 + kk * 4];
      #pragma unroll
      for (int v = 0; v < 4; ++v) b[v] = *(float4*)&Bs[(tx + 16 * v) * 68 + kk * 4];
      #pragma unroll
      for (int u = 0; u < 4; ++u)
        #pragma unroll
        for (int v = 0; v < 4; ++v) {
          acc[u][v] = fmaf(a[u].x, b[v].x, acc[u][v]);
          acc[u][v] = fmaf(a[u].y, b[v].y, acc[u][v]);
          acc[u][v] = fmaf(a[u].z, b[v].z, acc[u][v]);
          acc[u][v] = fmaf(a[u].w, b[v].w, acc[u][v]);
        }
    }
    __syncthreads();
  }
  #pragma unroll
  for (int u = 0; u < 4; ++u) {
    int r = row0 + ty + 16 * u;
    #pragma unroll
    for (int v = 0; v < 4; ++v) {
      int c = col0 + tx + 16 * v;
      if (c >= Nc) continue;
      size_t off = (size_t)r * Nc + c;
      float val = acc[u][v];
      if (EPI == 1) val += C[off];
      C[off] = val;
    }
  }
}

// ---------------- causal depthwise conv (K=4) + bias + silu, float4 over channels ----------------
__global__ __launch_bounds__(256) void conv_silu_kernel(const float* __restrict__ hz,
                                                        const float* __restrict__ cw,
                                                        const float* __restrict__ cb,
                                                        float* __restrict__ hs) {
  int idx = blockIdx.x * 256 + threadIdx.x;   // T*64
  int c4 = idx & 63;
  int t = idx >> 6;
  int l = t & (LSEQ - 1);
  float w[4][4];
  #pragma unroll
  for (int j = 0; j < 4; ++j) {
    float4 wv = *(const float4*)&cw[(c4 * 4 + j) * 4];
    w[j][0] = wv.x; w[j][1] = wv.y; w[j][2] = wv.z; w[j][3] = wv.w;
  }
  float4 acc = *(const float4*)&cb[c4 * 4];
  #pragma unroll
  for (int k = 0; k < 4; ++k) {
    int ll = l + k - 3;
    if (ll >= 0) {
      float4 v = *(const float4*)&hz[(size_t)(t + k - 3) * 512 + c4 * 4];
      acc.x = fmaf(v.x, w[0][k], acc.x);
      acc.y = fmaf(v.y, w[1][k], acc.y);
      acc.z = fmaf(v.z, w[2][k], acc.z);
      acc.w = fmaf(v.w, w[3][k], acc.w);
    }
  }
  acc.x = acc.x / (1.0f + __expf(-acc.x));
  acc.y = acc.y / (1.0f + __expf(-acc.y));
  acc.z = acc.z / (1.0f + __expf(-acc.z));
  acc.w = acc.w / (1.0f + __expf(-acc.w));
  *(float4*)&hs[(size_t)t * 256 + c4 * 4] = acc;
}

// ---------------- dt_proj (K=8) + softplus ----------------
__global__ __launch_bounds__(256) void dtproj_kernel(const float* __restrict__ xp,
                                                     const float* __restrict__ Wdt,
                                                     const float* __restrict__ bdt,
                                                     float* __restrict__ dtb) {
  int t = blockIdx.x;
  int i = threadIdx.x;
  const float* xr = xp + (size_t)t * 40;
  const float* wr = Wdt + i * 8;
  float s = bdt[i];
  #pragma unroll
  for (int r = 0; r < 8; ++r) s += xr[r] * wr[r];
  float sp = (s > 20.0f) ? s : log1pf(__expf(s));
  dtb[(size_t)t * 256 + i] = sp;
}

// ---------------- chunked selective scan: phase A (per-chunk P, S) ----------------
// grid (8, 16, 16chunks), block 256: i = by*16 + (tid>>4), n = tid&15
__global__ __launch_bounds__(256) void scanA_kernel(const float* __restrict__ dtb,
                                                    const float* __restrict__ hs,
                                                    const float* __restrict__ xp,
                                                    const float* __restrict__ A_log,
                                                    float* __restrict__ Pb,
                                                    float* __restrict__ Sb) {
  int b = blockIdx.x;
  int i = blockIdx.y * 16 + (threadIdx.x >> 4);
  int n = threadIdx.x & 15;
  int c = blockIdx.z;
  float A = -__expf(A_log[i * 16 + n]);
  float P = 1.0f, S = 0.0f;
  int t0 = b * LSEQ + c * 128;
  for (int l = 0; l < 128; ++l) {
    size_t t = t0 + l;
    float dtv = dtb[t * 256 + i];
    float hsv = hs[t * 256 + i];
    float bv = xp[t * 40 + 8 + n];
    float dA = __expf(dtv * A);
    P *= dA;
    S = fmaf(S, dA, dtv * bv * hsv);
  }
  int chain = b * 4096 + blockIdx.y * 256 + threadIdx.x;   // = b*4096 + i*16 + n
  Pb[c * 32768 + chain] = P;
  Sb[c * 32768 + chain] = S;
}

// ---------------- phase B: sequential combine over 16 chunks per chain ----------------
__global__ __launch_bounds__(256) void scanB_kernel(const float* __restrict__ Pb,
                                                    const float* __restrict__ Sb,
                                                    float* __restrict__ Ib) {
  int chain = blockIdx.x * 256 + threadIdx.x;   // 32768 chains
  float s = 0.0f;
  #pragma unroll
  for (int c = 0; c < 16; ++c) {
    Ib[c * 32768 + chain] = s;
    s = fmaf(s, Pb[c * 32768 + chain], Sb[c * 32768 + chain]);
  }
}

// ---------------- phase C: replay with init state, emit y = (h·C + hs·D)·silu(gate) ----------------
__global__ __launch_bounds__(256) void scanC_kernel(const float* __restrict__ dtb,
                                                    const float* __restrict__ hs,
                                                    const float* __restrict__ xp,
                                                    const float* __restrict__ A_log,
                                                    const float* __restrict__ Dp,
                                                    const float* __restrict__ hz,
                                                    const float* __restrict__ Ib,
                                                    float* __restrict__ y) {
  int b = blockIdx.x;
  int i = blockIdx.y * 16 + (threadIdx.x >> 4);
  int n = threadIdx.x & 15;
  int c = blockIdx.z;
  float A = -__expf(A_log[i * 16 + n]);
  float Dv = Dp[i];
  int chain = b * 4096 + blockIdx.y * 256 + threadIdx.x;
  float state = Ib[c * 32768 + chain];
  int t0 = b * LSEQ + c * 128;
  for (int l = 0; l < 128; ++l) {
    size_t t = t0 + l;
    float dtv = dtb[t * 256 + i];
    float hsv = hs[t * 256 + i];
    float bv = xp[t * 40 + 8 + n];
    float cv = xp[t * 40 + 24 + n];
    float dA = __expf(dtv * A);
    state = fmaf(state, dA, dtv * bv * hsv);
    float contrib = state * cv;
    contrib += __shfl_xor(contrib, 1, 16);
    contrib += __shfl_xor(contrib, 2, 16);
    contrib += __shfl_xor(contrib, 4, 16);
    contrib += __shfl_xor(contrib, 8, 16);
    if (n == 0) {
      float g = hz[t * 512 + 256 + i];
      y[t * 256 + i] = (contrib + hsv * Dv) * (g / (1.0f + __expf(-g)));
    }
  }
}

extern "C" void kernel_launch(void* const* d_in, const int* in_sizes, int n_in,
                              void* d_out, int out_size, void* d_ws, size_t ws_size,
                              hipStream_t stream) {
  const int* x           = (const int*)d_in[0];
  const float* embed     = (const float*)d_in[1];
  const float* in_proj_w = (const float*)d_in[2];
  const float* conv_w    = (const float*)d_in[3];
  const float* conv_b    = (const float*)d_in[4];
  const float* x_proj_w  = (const float*)d_in[5];
  const float* dt_proj_w = (const float*)d_in[6];
  const float* dt_proj_b = (const float*)d_in[7];
  const float* A_log     = (const float*)d_in[8];
  const float* Dp        = (const float*)d_in[9];
  const float* out_proj_w= (const float*)d_in[10];
  const float* norm_w    = (const float*)d_in[11];
  const float* norm_f_w  = (const float*)d_in[12];
  const float* head_w    = (const float*)d_in[13];
  const float* head_b    = (const float*)d_in[14];

  float* out = (float*)d_out;
  float* ws  = (float*)d_ws;

  // d_out scratch (dead before head GEMM overwrites all of d_out):
  float* hz  = out;                  // T*512
  float* hs  = out + 8388608;        // T*256
  float* dtb = out + 12582912;       // T*256
  float* y   = out + 16777216;       // T*256   (21.0M <= 33.5M elems)

  // ws scratch (17.3 MB)
  float* h  = ws;                    // T*128
  float* xp = ws + 2097152;          // T*40
  float* Pb = ws + 2752512;          // 16*32768
  float* Sb = ws + 3276800;          // 16*32768
  float* Ib = ws + 3801088;          // 16*32768

  embed_kernel<<<8192, 256, 0, stream>>>(x, embed, h);

  for (int l = 0; l < 32; ++l) {
    gemm_norm_kernel<0><<<dim3(256, 8), 256, 0, stream>>>(
        h, in_proj_w + (size_t)l * 512 * 128, norm_w + l * 128, hz, nullptr, 512);
    conv_silu_kernel<<<4096, 256, 0, stream>>>(hz, conv_w + l * 1024, conv_b + l * 256, hs);
    gemm_k_kernel<0><<<dim3(256, 1), 256, 0, stream>>>(
        hs, x_proj_w + (size_t)l * 40 * 256, xp, 40, 256);
    dtproj_kernel<<<16384, 256, 0, stream>>>(
        xp, dt_proj_w + l * 2048, dt_proj_b + l * 256, dtb);
    scanA_kernel<<<dim3(8, 16, 16), 256, 0, stream>>>(
        dtb, hs, xp, A_log + l * 4096, Pb, Sb);
    scanB_kernel<<<128, 256, 0, stream>>>(Pb, Sb, Ib);
    scanC_kernel<<<dim3(8, 16, 16), 256, 0, stream>>>(
        dtb, hs, xp, A_log + l * 4096, Dp + l * 256, hz, Ib, y);
    gemm_k_kernel<1><<<dim3(256, 2), 256, 0, stream>>>(
        y, out_proj_w + (size_t)l * 128 * 256, h, 128, 256);
  }

  gemm_norm_kernel<2><<<dim3(256, 32), 256, 0, stream>>>(
      h, head_w, norm_f_w, out, head_b, 2048);
}

// Round 4
// 6873.228 us; speedup vs baseline: 7.7887x; 1.2371x over previous
//
#include <hip/hip_runtime.h>
#include <hip/hip_bf16.h>

#define LSEQ 2048

typedef __attribute__((ext_vector_type(8))) short bf16x8;
typedef __attribute__((ext_vector_type(4))) float f32x4;
typedef __hip_bfloat16 bf16;

__device__ __forceinline__ void gload_lds16(const void* g, void* l) {
  __builtin_amdgcn_global_load_lds(
      (const __attribute__((address_space(1))) void*)g,
      (__attribute__((address_space(3))) void*)l, 16, 0, 0);
}

__device__ __forceinline__ void split_bf16(float v, bf16& h, bf16& l) {
  h = __float2bfloat16(v);
  l = __float2bfloat16(v - __bfloat162float(h));
}

// ---------------- embed ----------------
__global__ __launch_bounds__(256) void embed_kernel(const int* __restrict__ x,
                                                    const float* __restrict__ emb,
                                                    float* __restrict__ h) {
  int idx = blockIdx.x * 256 + threadIdx.x;   // T*128
  int t = idx >> 7;
  int d = idx & 127;
  h[idx] = emb[(size_t)x[t] * 128 + d];
}

// ---------------- weight casts (hi/lo split) ----------------
__global__ __launch_bounds__(256) void cast_split_kernel(const float* __restrict__ src,
                                                         bf16* __restrict__ hi,
                                                         bf16* __restrict__ lo, int n) {
  int i = blockIdx.x * 256 + threadIdx.x;
  if (i < n) { bf16 h, l; split_bf16(src[i], h, l); hi[i] = h; lo[i] = l; }
}

// x_proj: src [32][40][256] -> dst [32][64][256], rows 40..63 zero
__global__ __launch_bounds__(256) void cast_xproj_kernel(const float* __restrict__ src,
                                                         bf16* __restrict__ hi,
                                                         bf16* __restrict__ lo) {
  int i = blockIdx.x * 256 + threadIdx.x;   // 32*64*256
  int k = i & 255, n = (i >> 8) & 63, l = i >> 14;
  float v = (n < 40) ? src[((size_t)l * 40 + n) * 256 + k] : 0.f;
  bf16 h, lw; split_bf16(v, h, lw);
  hi[i] = h; lo[i] = lw;
}

// ---------------- rmsnorm -> bf16 hi/lo ----------------
__global__ __launch_bounds__(256) void rmsnorm_split_kernel(const float* __restrict__ hin,
                                                            const float* __restrict__ w,
                                                            bf16* __restrict__ hout_h,
                                                            bf16* __restrict__ hout_l) {
  int row = blockIdx.x * 4 + (threadIdx.x >> 6);
  int lane = threadIdx.x & 63;
  float2 v = *(const float2*)&hin[(size_t)row * 128 + lane * 2];
  float ss = v.x * v.x + v.y * v.y;
  #pragma unroll
  for (int m = 1; m < 64; m <<= 1) ss += __shfl_xor(ss, m);
  float rstd = rsqrtf(ss * (1.0f / 128.0f) + 1e-5f);
  float2 wv = *(const float2*)&w[lane * 2];
  float o0 = v.x * rstd * wv.x, o1 = v.y * rstd * wv.y;
  __hip_bfloat162 ph, pl;
  bf16 hh, ll;
  split_bf16(o0, hh, ll); ph.x = hh; pl.x = ll;
  split_bf16(o1, hh, ll); ph.y = hh; pl.y = ll;
  *(__hip_bfloat162*)&hout_h[(size_t)row * 128 + lane * 2] = ph;
  *(__hip_bfloat162*)&hout_l[(size_t)row * 128 + lane * 2] = pl;
}

// ---------------- split-bf16 MFMA GEMM: C[M,Nc](f32) = A @ W^T, A~AH+AL, W~WH+WL ----------------
// EPI 0: store   EPI 1: C += (residual)   EPI 2: store + bias
template <int BM, int BN, int EPI>
__global__ __launch_bounds__(256) void mfma_gemm(const bf16* __restrict__ AH,
                                                 const bf16* __restrict__ AL,
                                                 const bf16* __restrict__ WH,
                                                 const bf16* __restrict__ WL,
                                                 float* __restrict__ C,
                                                 const float* __restrict__ bias,
                                                 int Nc, int Kc) {
  constexpr int U = BM / 32, V = BN / 32;
  __shared__ bf16 AsH[BM * 64];
  __shared__ bf16 AsL[BM * 64];
  __shared__ bf16 BsH[BN * 64];
  __shared__ bf16 BsL[BN * 64];
  int tid = threadIdx.x;
  int lane = tid & 63, wid = tid >> 6;
  int wr = wid >> 1, wc = wid & 1;
  int row0 = blockIdx.x * BM, col0 = blockIdx.y * BN;
  int l15 = lane & 15, l4 = lane >> 4;
  f32x4 acc[U][V] = {};
  for (int k0 = 0; k0 < Kc; k0 += 64) {
    __syncthreads();
    #pragma unroll
    for (int it = 0; it < BM / 32; ++it) {
      int chunk = it * 256 + tid;
      int r = chunk >> 3;
      int clog = (chunk & 7) ^ (r & 7);
      size_t goff = (size_t)(row0 + r) * Kc + k0 + clog * 8;
      gload_lds16(AH + goff, &AsH[chunk * 8]);
      gload_lds16(AL + goff, &AsL[chunk * 8]);
    }
    #pragma unroll
    for (int it = 0; it < BN / 32; ++it) {
      int chunk = it * 256 + tid;
      int r = chunk >> 3;
      int clog = (chunk & 7) ^ (r & 7);
      size_t goff = (size_t)(col0 + r) * Kc + k0 + clog * 8;
      gload_lds16(WH + goff, &BsH[chunk * 8]);
      gload_lds16(WL + goff, &BsL[chunk * 8]);
    }
    __syncthreads();
    #pragma unroll
    for (int kk = 0; kk < 2; ++kk) {
      bf16x8 afh[U], afl[U], bfh[V], bfl[V];
      #pragma unroll
      for (int u = 0; u < U; ++u) {
        int r = wr * (BM / 2) + u * 16 + l15;
        int csw = (kk * 4 + l4) ^ (r & 7);
        afh[u] = *(const bf16x8*)&AsH[r * 64 + csw * 8];
        afl[u] = *(const bf16x8*)&AsL[r * 64 + csw * 8];
      }
      #pragma unroll
      for (int v = 0; v < V; ++v) {
        int r = wc * (BN / 2) + v * 16 + l15;
        int csw = (kk * 4 + l4) ^ (r & 7);
        bfh[v] = *(const bf16x8*)&BsH[r * 64 + csw * 8];
        bfl[v] = *(const bf16x8*)&BsL[r * 64 + csw * 8];
      }
      #pragma unroll
      for (int u = 0; u < U; ++u)
        #pragma unroll
        for (int v = 0; v < V; ++v) {
          acc[u][v] = __builtin_amdgcn_mfma_f32_16x16x32_bf16(afh[u], bfh[v], acc[u][v], 0, 0, 0);
          acc[u][v] = __builtin_amdgcn_mfma_f32_16x16x32_bf16(afl[u], bfh[v], acc[u][v], 0, 0, 0);
          acc[u][v] = __builtin_amdgcn_mfma_f32_16x16x32_bf16(afh[u], bfl[v], acc[u][v], 0, 0, 0);
        }
    }
  }
  #pragma unroll
  for (int u = 0; u < U; ++u) {
    int rbase = row0 + wr * (BM / 2) + u * 16 + l4 * 4;
    #pragma unroll
    for (int v = 0; v < V; ++v) {
      int col = col0 + wc * (BN / 2) + v * 16 + l15;
      #pragma unroll
      for (int q = 0; q < 4; ++q) {
        size_t off = (size_t)(rbase + q) * Nc + col;
        float val = acc[u][v][q];
        if (EPI == 1) val += C[off];
        if (EPI == 2) val += bias[col];
        C[off] = val;
      }
    }
  }
}

// ---------------- causal depthwise conv (K=4) + bias + silu; writes f32 + bf16 hi/lo ----------------
__global__ __launch_bounds__(256) void conv_silu_kernel(const float* __restrict__ hz,
                                                        const float* __restrict__ cw,
                                                        const float* __restrict__ cb,
                                                        float* __restrict__ hs,
                                                        bf16* __restrict__ hs_h,
                                                        bf16* __restrict__ hs_l) {
  int idx = blockIdx.x * 256 + threadIdx.x;   // T*64
  int c4 = idx & 63;
  int t = idx >> 6;
  int l = t & (LSEQ - 1);
  float w[4][4];
  #pragma unroll
  for (int j = 0; j < 4; ++j) {
    float4 wv = *(const float4*)&cw[(c4 * 4 + j) * 4];
    w[j][0] = wv.x; w[j][1] = wv.y; w[j][2] = wv.z; w[j][3] = wv.w;
  }
  float4 acc = *(const float4*)&cb[c4 * 4];
  #pragma unroll
  for (int k = 0; k < 4; ++k) {
    int ll = l + k - 3;
    if (ll >= 0) {
      float4 v = *(const float4*)&hz[(size_t)(t + k - 3) * 512 + c4 * 4];
      acc.x = fmaf(v.x, w[0][k], acc.x);
      acc.y = fmaf(v.y, w[1][k], acc.y);
      acc.z = fmaf(v.z, w[2][k], acc.z);
      acc.w = fmaf(v.w, w[3][k], acc.w);
    }
  }
  acc.x = acc.x / (1.0f + __expf(-acc.x));
  acc.y = acc.y / (1.0f + __expf(-acc.y));
  acc.z = acc.z / (1.0f + __expf(-acc.z));
  acc.w = acc.w / (1.0f + __expf(-acc.w));
  *(float4*)&hs[(size_t)t * 256 + c4 * 4] = acc;
  bf16 hh, ll2;
  __hip_bfloat162 h01, h23, l01, l23;
  split_bf16(acc.x, hh, ll2); h01.x = hh; l01.x = ll2;
  split_bf16(acc.y, hh, ll2); h01.y = hh; l01.y = ll2;
  split_bf16(acc.z, hh, ll2); h23.x = hh; l23.x = ll2;
  split_bf16(acc.w, hh, ll2); h23.y = hh; l23.y = ll2;
  *(__hip_bfloat162*)&hs_h[(size_t)t * 256 + c4 * 4] = h01;
  *(__hip_bfloat162*)&hs_h[(size_t)t * 256 + c4 * 4 + 2] = h23;
  *(__hip_bfloat162*)&hs_l[(size_t)t * 256 + c4 * 4] = l01;
  *(__hip_bfloat162*)&hs_l[(size_t)t * 256 + c4 * 4 + 2] = l23;
}

// ---------------- dt_proj (K=8) + softplus; xp stride 64 ----------------
__global__ __launch_bounds__(256) void dtproj_kernel(const float* __restrict__ xp,
                                                     const float* __restrict__ Wdt,
                                                     const float* __restrict__ bdt,
                                                     float* __restrict__ dtb) {
  int t = blockIdx.x;
  int i = threadIdx.x;
  const float* xr = xp + (size_t)t * 64;
  const float* wr = Wdt + i * 8;
  float s = bdt[i];
  #pragma unroll
  for (int r = 0; r < 8; ++r) s += xr[r] * wr[r];
  float sp = (s > 20.0f) ? s : log1pf(__expf(s));
  dtb[(size_t)t * 256 + i] = sp;
}

// ---------------- chunked selective scan: phase A ----------------
__global__ __launch_bounds__(256) void scanA_kernel(const float* __restrict__ dtb,
                                                    const float* __restrict__ hs,
                                                    const float* __restrict__ xp,
                                                    const float* __restrict__ A_log,
                                                    float* __restrict__ Pb,
                                                    float* __restrict__ Sb) {
  int b = blockIdx.x;
  int i = blockIdx.y * 16 + (threadIdx.x >> 4);
  int n = threadIdx.x & 15;
  int c = blockIdx.z;
  float A = -__expf(A_log[i * 16 + n]);
  float P = 1.0f, S = 0.0f;
  int t0 = b * LSEQ + c * 128;
  for (int l = 0; l < 128; ++l) {
    size_t t = t0 + l;
    float dtv = dtb[t * 256 + i];
    float hsv = hs[t * 256 + i];
    float bv = xp[t * 64 + 8 + n];
    float dA = __expf(dtv * A);
    P *= dA;
    S = fmaf(S, dA, dtv * bv * hsv);
  }
  int chain = b * 4096 + blockIdx.y * 256 + threadIdx.x;
  Pb[c * 32768 + chain] = P;
  Sb[c * 32768 + chain] = S;
}

// ---------------- phase B ----------------
__global__ __launch_bounds__(256) void scanB_kernel(const float* __restrict__ Pb,
                                                    const float* __restrict__ Sb,
                                                    float* __restrict__ Ib) {
  int chain = blockIdx.x * 256 + threadIdx.x;
  float s = 0.0f;
  #pragma unroll
  for (int c = 0; c < 16; ++c) {
    Ib[c * 32768 + chain] = s;
    s = fmaf(s, Pb[c * 32768 + chain], Sb[c * 32768 + chain]);
  }
}

// ---------------- phase C: emit y (bf16 hi/lo) ----------------
__global__ __launch_bounds__(256) void scanC_kernel(const float* __restrict__ dtb,
                                                    const float* __restrict__ hs,
                                                    const float* __restrict__ xp,
                                                    const float* __restrict__ A_log,
                                                    const float* __restrict__ Dp,
                                                    const float* __restrict__ hz,
                                                    const float* __restrict__ Ib,
                                                    bf16* __restrict__ y_h,
                                                    bf16* __restrict__ y_l) {
  int b = blockIdx.x;
  int i = blockIdx.y * 16 + (threadIdx.x >> 4);
  int n = threadIdx.x & 15;
  int c = blockIdx.z;
  float A = -__expf(A_log[i * 16 + n]);
  float Dv = Dp[i];
  int chain = b * 4096 + blockIdx.y * 256 + threadIdx.x;
  float state = Ib[c * 32768 + chain];
  int t0 = b * LSEQ + c * 128;
  for (int l = 0; l < 128; ++l) {
    size_t t = t0 + l;
    float dtv = dtb[t * 256 + i];
    float hsv = hs[t * 256 + i];
    float bv = xp[t * 64 + 8 + n];
    float cv = xp[t * 64 + 24 + n];
    float dA = __expf(dtv * A);
    state = fmaf(state, dA, dtv * bv * hsv);
    float contrib = state * cv;
    contrib += __shfl_xor(contrib, 1, 16);
    contrib += __shfl_xor(contrib, 2, 16);
    contrib += __shfl_xor(contrib, 4, 16);
    contrib += __shfl_xor(contrib, 8, 16);
    if (n == 0) {
      float g = hz[t * 512 + 256 + i];
      float val = (contrib + hsv * Dv) * (g / (1.0f + __expf(-g)));
      bf16 hh, ll;
      split_bf16(val, hh, ll);
      y_h[t * 256 + i] = hh;
      y_l[t * 256 + i] = ll;
    }
  }
}

extern "C" void kernel_launch(void* const* d_in, const int* in_sizes, int n_in,
                              void* d_out, int out_size, void* d_ws, size_t ws_size,
                              hipStream_t stream) {
  const int* x           = (const int*)d_in[0];
  const float* embed     = (const float*)d_in[1];
  const float* in_proj_w = (const float*)d_in[2];
  const float* conv_w    = (const float*)d_in[3];
  const float* conv_b    = (const float*)d_in[4];
  const float* x_proj_w  = (const float*)d_in[5];
  const float* dt_proj_w = (const float*)d_in[6];
  const float* dt_proj_b = (const float*)d_in[7];
  const float* A_log     = (const float*)d_in[8];
  const float* Dp        = (const float*)d_in[9];
  const float* out_proj_w= (const float*)d_in[10];
  const float* norm_w    = (const float*)d_in[11];
  const float* norm_f_w  = (const float*)d_in[12];
  const float* head_w    = (const float*)d_in[13];
  const float* head_b    = (const float*)d_in[14];

  float* out = (float*)d_out;
  float* ws  = (float*)d_ws;

  // ---- d_out scratch map (f32 word offsets; total exactly 33,554,432) ----
  float* hz      = out;                          // 8,388,608  (T*512)
  float* hs      = out + 8388608;                // 4,194,304  (T*256)
  float* dtb     = out + 12582912;               // 4,194,304  (T*256)
  float* h       = out + 16777216;               // 2,097,152  (T*128 residual)
  float* xp      = out + 18874368;               // 1,048,576  (T*64)
  bf16*  hs_h    = (bf16*)(out + 19922944);      // T*256 bf16
  bf16*  hs_l    = (bf16*)(out + 22020096);      // T*256 bf16
  bf16*  y_h     = (bf16*)(out + 24117248);      // T*256 bf16
  bf16*  y_l     = (bf16*)(out + 26214400);      // T*256 bf16
  bf16*  w_in_h  = (bf16*)(out + 28311552);      // 32*512*128
  bf16*  w_in_l  = (bf16*)(out + 29360128);
  bf16*  w_x_h   = (bf16*)(out + 30408704);      // 32*64*256 (padded)
  bf16*  w_x_l   = (bf16*)(out + 30670848);
  bf16*  w_out_h = (bf16*)(out + 30932992);      // 32*128*256
  bf16*  w_out_l = (bf16*)(out + 31457280);
  float* Pb      = out + 31981568;               // 16*32768
  float* Sb      = out + 32505856;
  float* Ib      = out + 33030144;               // ends 33,554,432

  // ---- ws scratch (9.4 MB) — live through the head GEMM ----
  bf16* hn_h     = (bf16*)ws;                    // T*128 bf16
  bf16* hn_l     = (bf16*)(ws + 1048576);        // T*128 bf16
  bf16* w_head_h = (bf16*)(ws + 2097152);        // 2048*128 bf16
  bf16* w_head_l = (bf16*)(ws + 2228224);        // 2048*128 bf16

  cast_split_kernel<<<8192, 256, 0, stream>>>(in_proj_w, w_in_h, w_in_l, 2097152);
  cast_xproj_kernel<<<2048, 256, 0, stream>>>(x_proj_w, w_x_h, w_x_l);
  cast_split_kernel<<<4096, 256, 0, stream>>>(out_proj_w, w_out_h, w_out_l, 1048576);
  cast_split_kernel<<<1024, 256, 0, stream>>>(head_w, w_head_h, w_head_l, 262144);

  embed_kernel<<<8192, 256, 0, stream>>>(x, embed, h);

  for (int l = 0; l < 32; ++l) {
    rmsnorm_split_kernel<<<4096, 256, 0, stream>>>(h, norm_w + l * 128, hn_h, hn_l);
    mfma_gemm<128, 128, 0><<<dim3(128, 4), 256, 0, stream>>>(
        hn_h, hn_l, w_in_h + (size_t)l * 512 * 128, w_in_l + (size_t)l * 512 * 128,
        hz, nullptr, 512, 128);
    conv_silu_kernel<<<4096, 256, 0, stream>>>(hz, conv_w + l * 1024, conv_b + l * 256,
                                               hs, hs_h, hs_l);
    mfma_gemm<64, 64, 0><<<dim3(256, 1), 256, 0, stream>>>(
        hs_h, hs_l, w_x_h + (size_t)l * 64 * 256, w_x_l + (size_t)l * 64 * 256,
        xp, nullptr, 64, 256);
    dtproj_kernel<<<16384, 256, 0, stream>>>(
        xp, dt_proj_w + l * 2048, dt_proj_b + l * 256, dtb);
    scanA_kernel<<<dim3(8, 16, 16), 256, 0, stream>>>(
        dtb, hs, xp, A_log + l * 4096, Pb, Sb);
    scanB_kernel<<<128, 256, 0, stream>>>(Pb, Sb, Ib);
    scanC_kernel<<<dim3(8, 16, 16), 256, 0, stream>>>(
        dtb, hs, xp, A_log + l * 4096, Dp + l * 256, hz, Ib, y_h, y_l);
    mfma_gemm<64, 128, 1><<<dim3(256, 1), 256, 0, stream>>>(
        y_h, y_l, w_out_h + (size_t)l * 128 * 256, w_out_l + (size_t)l * 128 * 256,
        h, nullptr, 128, 256);
  }

  rmsnorm_split_kernel<<<4096, 256, 0, stream>>>(h, norm_f_w, hn_h, hn_l);
  mfma_gemm<128, 128, 2><<<dim3(128, 16), 256, 0, stream>>>(
      hn_h, hn_l, w_head_h, w_head_l, out, head_b, 2048, 128);
}

// Round 6
// 6773.020 us; speedup vs baseline: 7.9040x; 1.0148x over previous
//
#include <hip/hip_runtime.h>
#include <hip/hip_bf16.h>

#define LSEQ 2048

typedef __attribute__((ext_vector_type(8))) short bf16x8;
typedef __attribute__((ext_vector_type(4))) float f32x4;
typedef __hip_bfloat16 bf16;

__device__ __forceinline__ void gload_lds16(const void* g, void* l) {
  __builtin_amdgcn_global_load_lds(
      (const __attribute__((address_space(1))) void*)g,
      (__attribute__((address_space(3))) void*)l, 16, 0, 0);
}

__device__ __forceinline__ void split_bf16(float v, bf16& h, bf16& l) {
  h = __float2bfloat16(v);
  l = __float2bfloat16(v - __bfloat162float(h));
}

// ---------------- embed ----------------
__global__ __launch_bounds__(256) void embed_kernel(const int* __restrict__ x,
                                                    const float* __restrict__ emb,
                                                    float* __restrict__ h) {
  int idx = blockIdx.x * 256 + threadIdx.x;   // T*128
  int t = idx >> 7;
  int d = idx & 127;
  h[idx] = emb[(size_t)x[t] * 128 + d];
}

// ---------------- weight casts (hi/lo split) ----------------
__global__ __launch_bounds__(256) void cast_split_kernel(const float* __restrict__ src,
                                                         bf16* __restrict__ hi,
                                                         bf16* __restrict__ lo, int n) {
  int i = blockIdx.x * 256 + threadIdx.x;
  if (i < n) { bf16 h, l; split_bf16(src[i], h, l); hi[i] = h; lo[i] = l; }
}

// x_proj: src [32][40][256] -> dst [32][64][256], rows 40..63 zero
__global__ __launch_bounds__(256) void cast_xproj_kernel(const float* __restrict__ src,
                                                         bf16* __restrict__ hi,
                                                         bf16* __restrict__ lo) {
  int i = blockIdx.x * 256 + threadIdx.x;   // 32*64*256
  int k = i & 255, n = (i >> 8) & 63, l = i >> 14;
  float v = (n < 40) ? src[((size_t)l * 40 + n) * 256 + k] : 0.f;
  bf16 h, lw; split_bf16(v, h, lw);
  hi[i] = h; lo[i] = lw;
}

// ---------------- rmsnorm -> bf16 hi/lo ----------------
__global__ __launch_bounds__(256) void rmsnorm_split_kernel(const float* __restrict__ hin,
                                                            const float* __restrict__ w,
                                                            bf16* __restrict__ hout_h,
                                                            bf16* __restrict__ hout_l) {
  int row = blockIdx.x * 4 + (threadIdx.x >> 6);
  int lane = threadIdx.x & 63;
  float2 v = *(const float2*)&hin[(size_t)row * 128 + lane * 2];
  float ss = v.x * v.x + v.y * v.y;
  #pragma unroll
  for (int m = 1; m < 64; m <<= 1) ss += __shfl_xor(ss, m);
  float rstd = rsqrtf(ss * (1.0f / 128.0f) + 1e-5f);
  float2 wv = *(const float2*)&w[lane * 2];
  float o0 = v.x * rstd * wv.x, o1 = v.y * rstd * wv.y;
  __hip_bfloat162 ph, pl;
  bf16 hh, ll;
  split_bf16(o0, hh, ll); ph.x = hh; pl.x = ll;
  split_bf16(o1, hh, ll); ph.y = hh; pl.y = ll;
  *(__hip_bfloat162*)&hout_h[(size_t)row * 128 + lane * 2] = ph;
  *(__hip_bfloat162*)&hout_l[(size_t)row * 128 + lane * 2] = pl;
}

// ================= generic split-bf16 MFMA GEMM =================
// EPI 1: C += (residual)   EPI 2: C = val + bias
template <int BM, int BN, int WR, int WC, int EPI>
__global__ __launch_bounds__(256) void mfma_gemm(const bf16* __restrict__ AH,
                                                 const bf16* __restrict__ AL,
                                                 const bf16* __restrict__ WH,
                                                 const bf16* __restrict__ WL,
                                                 float* __restrict__ C,
                                                 const float* __restrict__ bias,
                                                 int Nc, int Kc) {
  constexpr int WTM = BM / WR, WTN = BN / WC;
  constexpr int U = WTM / 16, V = WTN / 16;
  __shared__ bf16 AsH[BM * 64];
  __shared__ bf16 AsL[BM * 64];
  __shared__ bf16 BsH[BN * 64];
  __shared__ bf16 BsL[BN * 64];
  int tid = threadIdx.x;
  int lane = tid & 63, wid = tid >> 6;
  int wr = wid / WC, wc = wid % WC;
  int row0 = blockIdx.x * BM, col0 = blockIdx.y * BN;
  int l15 = lane & 15, l4 = lane >> 4;
  f32x4 acc[U][V] = {};
  for (int k0 = 0; k0 < Kc; k0 += 64) {
    __syncthreads();
    #pragma unroll
    for (int it = 0; it < BM / 32; ++it) {
      int chunk = it * 256 + tid;
      int r = chunk >> 3;
      int clog = (chunk & 7) ^ (r & 7);
      size_t goff = (size_t)(row0 + r) * Kc + k0 + clog * 8;
      gload_lds16(AH + goff, &AsH[chunk * 8]);
      gload_lds16(AL + goff, &AsL[chunk * 8]);
    }
    #pragma unroll
    for (int it = 0; it < BN / 32; ++it) {
      int chunk = it * 256 + tid;
      int r = chunk >> 3;
      int clog = (chunk & 7) ^ (r & 7);
      size_t goff = (size_t)(col0 + r) * Kc + k0 + clog * 8;
      gload_lds16(WH + goff, &BsH[chunk * 8]);
      gload_lds16(WL + goff, &BsL[chunk * 8]);
    }
    __syncthreads();
    #pragma unroll
    for (int kk = 0; kk < 2; ++kk) {
      bf16x8 afh[U], afl[U], bfh[V], bfl[V];
      #pragma unroll
      for (int u = 0; u < U; ++u) {
        int r = wr * WTM + u * 16 + l15;
        int csw = (kk * 4 + l4) ^ (r & 7);
        afh[u] = *(const bf16x8*)&AsH[r * 64 + csw * 8];
        afl[u] = *(const bf16x8*)&AsL[r * 64 + csw * 8];
      }
      #pragma unroll
      for (int v = 0; v < V; ++v) {
        int r = wc * WTN + v * 16 + l15;
        int csw = (kk * 4 + l4) ^ (r & 7);
        bfh[v] = *(const bf16x8*)&BsH[r * 64 + csw * 8];
        bfl[v] = *(const bf16x8*)&BsL[r * 64 + csw * 8];
      }
      #pragma unroll
      for (int u = 0; u < U; ++u)
        #pragma unroll
        for (int v = 0; v < V; ++v) {
          acc[u][v] = __builtin_amdgcn_mfma_f32_16x16x32_bf16(afh[u], bfh[v], acc[u][v], 0, 0, 0);
          acc[u][v] = __builtin_amdgcn_mfma_f32_16x16x32_bf16(afl[u], bfh[v], acc[u][v], 0, 0, 0);
          acc[u][v] = __builtin_amdgcn_mfma_f32_16x16x32_bf16(afh[u], bfl[v], acc[u][v], 0, 0, 0);
        }
    }
  }
  #pragma unroll
  for (int u = 0; u < U; ++u) {
    int rbase = row0 + wr * WTM + u * 16 + l4 * 4;
    #pragma unroll
    for (int v = 0; v < V; ++v) {
      int col = col0 + wc * WTN + v * 16 + l15;
      #pragma unroll
      for (int q = 0; q < 4; ++q) {
        size_t off = (size_t)(rbase + q) * Nc + col;
        float val = acc[u][v][q];
        if (EPI == 1) val += C[off];
        if (EPI == 2) val += bias[col];
        C[off] = val;
      }
    }
  }
}

// ================= in_proj: GEMM (128x128, K=128) writing hzx(f32) / silu(gate)(f32) =================
__global__ __launch_bounds__(256) void inproj_kernel(const bf16* __restrict__ AH,
                                                     const bf16* __restrict__ AL,
                                                     const bf16* __restrict__ WH,
                                                     const bf16* __restrict__ WL,
                                                     float* __restrict__ hzx,
                                                     float* __restrict__ gate_f) {
  constexpr int BM = 128, BN = 128;
  __shared__ bf16 AsH[BM * 64];
  __shared__ bf16 AsL[BM * 64];
  __shared__ bf16 BsH[BN * 64];
  __shared__ bf16 BsL[BN * 64];
  int tid = threadIdx.x;
  int lane = tid & 63, wid = tid >> 6;
  int wr = wid >> 1, wc = wid & 1;
  int row0 = blockIdx.x * BM, col0 = blockIdx.y * BN;
  int l15 = lane & 15, l4 = lane >> 4;
  f32x4 acc[4][4] = {};
  for (int k0 = 0; k0 < 128; k0 += 64) {
    __syncthreads();
    #pragma unroll
    for (int it = 0; it < 4; ++it) {
      int chunk = it * 256 + tid;
      int r = chunk >> 3;
      int clog = (chunk & 7) ^ (r & 7);
      size_t goff = (size_t)(row0 + r) * 128 + k0 + clog * 8;
      gload_lds16(AH + goff, &AsH[chunk * 8]);
      gload_lds16(AL + goff, &AsL[chunk * 8]);
      size_t woff = (size_t)(col0 + r) * 128 + k0 + clog * 8;
      gload_lds16(WH + woff, &BsH[chunk * 8]);
      gload_lds16(WL + woff, &BsL[chunk * 8]);
    }
    __syncthreads();
    #pragma unroll
    for (int kk = 0; kk < 2; ++kk) {
      bf16x8 afh[4], afl[4], bfh[4], bfl[4];
      #pragma unroll
      for (int u = 0; u < 4; ++u) {
        int r = wr * 64 + u * 16 + l15;
        int csw = (kk * 4 + l4) ^ (r & 7);
        afh[u] = *(const bf16x8*)&AsH[r * 64 + csw * 8];
        afl[u] = *(const bf16x8*)&AsL[r * 64 + csw * 8];
      }
      #pragma unroll
      for (int v = 0; v < 4; ++v) {
        int r = wc * 64 + v * 16 + l15;
        int csw = (kk * 4 + l4) ^ (r & 7);
        bfh[v] = *(const bf16x8*)&BsH[r * 64 + csw * 8];
        bfl[v] = *(const bf16x8*)&BsL[r * 64 + csw * 8];
      }
      #pragma unroll
      for (int u = 0; u < 4; ++u)
        #pragma unroll
        for (int v = 0; v < 4; ++v) {
          acc[u][v] = __builtin_amdgcn_mfma_f32_16x16x32_bf16(afh[u], bfh[v], acc[u][v], 0, 0, 0);
          acc[u][v] = __builtin_amdgcn_mfma_f32_16x16x32_bf16(afl[u], bfh[v], acc[u][v], 0, 0, 0);
          acc[u][v] = __builtin_amdgcn_mfma_f32_16x16x32_bf16(afh[u], bfl[v], acc[u][v], 0, 0, 0);
        }
    }
  }
  bool isgate = (col0 >= 256);
  #pragma unroll
  for (int u = 0; u < 4; ++u) {
    int rbase = row0 + wr * 64 + u * 16 + l4 * 4;
    #pragma unroll
    for (int v = 0; v < 4; ++v) {
      int col = col0 + wc * 64 + v * 16 + l15;
      #pragma unroll
      for (int q = 0; q < 4; ++q) {
        float val = acc[u][v][q];
        if (!isgate) {
          hzx[(size_t)(rbase + q) * 256 + col] = val;
        } else {
          float s = val / (1.0f + __expf(-val));
          gate_f[(size_t)(rbase + q) * 256 + (col - 256)] = s;
        }
      }
    }
  }
}

// ================= x_proj (32x64, K=256) + fused dt_proj/softplus =================
__global__ __launch_bounds__(256) void xproj_dt_kernel(const bf16* __restrict__ AH,
                                                       const bf16* __restrict__ AL,
                                                       const bf16* __restrict__ WH,
                                                       const bf16* __restrict__ WL,
                                                       const float* __restrict__ Wdt,
                                                       const float* __restrict__ bdt,
                                                       float* __restrict__ xp,
                                                       float* __restrict__ dtb) {
  constexpr int BM = 32, BN = 64;
  __shared__ bf16 AsH[BM * 64];
  __shared__ bf16 AsL[BM * 64];
  __shared__ bf16 BsH[BN * 64];
  __shared__ bf16 BsL[BN * 64];
  __shared__ float xq[32][8];
  int tid = threadIdx.x;
  int lane = tid & 63, wid = tid >> 6;
  int wr = wid >> 1, wc = wid & 1;   // wave tile 16x32
  int row0 = blockIdx.x * BM;
  int l15 = lane & 15, l4 = lane >> 4;
  f32x4 acc[1][2] = {};
  for (int k0 = 0; k0 < 256; k0 += 64) {
    __syncthreads();
    {
      int chunk = tid;                    // 256 chunks = BM*8
      int r = chunk >> 3;
      int clog = (chunk & 7) ^ (r & 7);
      size_t goff = (size_t)(row0 + r) * 256 + k0 + clog * 8;
      gload_lds16(AH + goff, &AsH[chunk * 8]);
      gload_lds16(AL + goff, &AsL[chunk * 8]);
    }
    #pragma unroll
    for (int it = 0; it < 2; ++it) {
      int chunk = it * 256 + tid;
      int r = chunk >> 3;
      int clog = (chunk & 7) ^ (r & 7);
      size_t goff = (size_t)r * 256 + k0 + clog * 8;
      gload_lds16(WH + goff, &BsH[chunk * 8]);
      gload_lds16(WL + goff, &BsL[chunk * 8]);
    }
    __syncthreads();
    #pragma unroll
    for (int kk = 0; kk < 2; ++kk) {
      bf16x8 afh, afl, bfh[2], bfl[2];
      {
        int r = wr * 16 + l15;
        int csw = (kk * 4 + l4) ^ (r & 7);
        afh = *(const bf16x8*)&AsH[r * 64 + csw * 8];
        afl = *(const bf16x8*)&AsL[r * 64 + csw * 8];
      }
      #pragma unroll
      for (int v = 0; v < 2; ++v) {
        int r = wc * 32 + v * 16 + l15;
        int csw = (kk * 4 + l4) ^ (r & 7);
        bfh[v] = *(const bf16x8*)&BsH[r * 64 + csw * 8];
        bfl[v] = *(const bf16x8*)&BsL[r * 64 + csw * 8];
      }
      #pragma unroll
      for (int v = 0; v < 2; ++v) {
        acc[0][v] = __builtin_amdgcn_mfma_f32_16x16x32_bf16(afh, bfh[v], acc[0][v], 0, 0, 0);
        acc[0][v] = __builtin_amdgcn_mfma_f32_16x16x32_bf16(afl, bfh[v], acc[0][v], 0, 0, 0);
        acc[0][v] = __builtin_amdgcn_mfma_f32_16x16x32_bf16(afh, bfl[v], acc[0][v], 0, 0, 0);
      }
    }
  }
  // epilogue: write xp; stash cols 0..7 into LDS
  {
    int rbase = wr * 16 + l4 * 4;
    #pragma unroll
    for (int v = 0; v < 2; ++v) {
      int col = wc * 32 + v * 16 + l15;
      #pragma unroll
      for (int q = 0; q < 4; ++q) {
        float val = acc[0][v][q];
        xp[(size_t)(row0 + rbase + q) * 64 + col] = val;
        if (col < 8) xq[rbase + q][col] = val;
      }
    }
  }
  __syncthreads();
  // dt phase: thread i computes dt for all 32 tokens of this tile
  {
    int i = tid;
    const float* wr8 = Wdt + i * 8;
    float w0 = wr8[0], w1 = wr8[1], w2 = wr8[2], w3 = wr8[3];
    float w4 = wr8[4], w5 = wr8[5], w6 = wr8[6], w7 = wr8[7];
    float bv = bdt[i];
    #pragma unroll 4
    for (int tt = 0; tt < 32; ++tt) {
      const float* q = xq[tt];
      float s = bv;
      s = fmaf(q[0], w0, s); s = fmaf(q[1], w1, s);
      s = fmaf(q[2], w2, s); s = fmaf(q[3], w3, s);
      s = fmaf(q[4], w4, s); s = fmaf(q[5], w5, s);
      s = fmaf(q[6], w6, s); s = fmaf(q[7], w7, s);
      float sp = (s > 20.0f) ? s : log1pf(__expf(s));
      dtb[(size_t)(row0 + tt) * 256 + i] = sp;
    }
  }
}

// ---------------- causal depthwise conv (K=4) + bias + silu -> bf16 hi/lo ----------------
__global__ __launch_bounds__(256) void conv_silu_kernel(const float* __restrict__ hzx,
                                                        const float* __restrict__ cw,
                                                        const float* __restrict__ cb,
                                                        bf16* __restrict__ hs_h,
                                                        bf16* __restrict__ hs_l) {
  int idx = blockIdx.x * 256 + threadIdx.x;   // T*64
  int c4 = idx & 63;
  int t = idx >> 6;
  int l = t & (LSEQ - 1);
  float w[4][4];
  #pragma unroll
  for (int j = 0; j < 4; ++j) {
    float4 wv = *(const float4*)&cw[(c4 * 4 + j) * 4];
    w[j][0] = wv.x; w[j][1] = wv.y; w[j][2] = wv.z; w[j][3] = wv.w;
  }
  float4 acc = *(const float4*)&cb[c4 * 4];
  #pragma unroll
  for (int k = 0; k < 4; ++k) {
    int ll = l + k - 3;
    if (ll >= 0) {
      float4 v = *(const float4*)&hzx[(size_t)(t + k - 3) * 256 + c4 * 4];
      acc.x = fmaf(v.x, w[0][k], acc.x);
      acc.y = fmaf(v.y, w[1][k], acc.y);
      acc.z = fmaf(v.z, w[2][k], acc.z);
      acc.w = fmaf(v.w, w[3][k], acc.w);
    }
  }
  acc.x = acc.x / (1.0f + __expf(-acc.x));
  acc.y = acc.y / (1.0f + __expf(-acc.y));
  acc.z = acc.z / (1.0f + __expf(-acc.z));
  acc.w = acc.w / (1.0f + __expf(-acc.w));
  bf16 hh, ll2;
  __hip_bfloat162 h01, h23, l01, l23;
  split_bf16(acc.x, hh, ll2); h01.x = hh; l01.x = ll2;
  split_bf16(acc.y, hh, ll2); h01.y = hh; l01.y = ll2;
  split_bf16(acc.z, hh, ll2); h23.x = hh; l23.x = ll2;
  split_bf16(acc.w, hh, ll2); h23.y = hh; l23.y = ll2;
  *(__hip_bfloat162*)&hs_h[(size_t)t * 256 + c4 * 4] = h01;
  *(__hip_bfloat162*)&hs_h[(size_t)t * 256 + c4 * 4 + 2] = h23;
  *(__hip_bfloat162*)&hs_l[(size_t)t * 256 + c4 * 4] = l01;
  *(__hip_bfloat162*)&hs_l[(size_t)t * 256 + c4 * 4 + 2] = l23;
}

// ---------------- chunked selective scan: phase A (chunks 0..14) ----------------
__global__ __launch_bounds__(256) void scanA_kernel(const float* __restrict__ dtb,
                                                    const bf16* __restrict__ hs_h,
                                                    const bf16* __restrict__ hs_l,
                                                    const float* __restrict__ xp,
                                                    const float* __restrict__ A_log,
                                                    float* __restrict__ Pb,
                                                    float* __restrict__ Sb) {
  int b = blockIdx.x;
  int i = blockIdx.y * 16 + (threadIdx.x >> 4);
  int n = threadIdx.x & 15;
  int c = blockIdx.z;
  float A = -__expf(A_log[i * 16 + n]);
  float P = 1.0f, S = 0.0f;
  int t0 = b * LSEQ + c * 128;
  for (int l = 0; l < 128; ++l) {
    size_t t = t0 + l;
    float dtv = dtb[t * 256 + i];
    float hsv = __bfloat162float(hs_h[t * 256 + i]) + __bfloat162float(hs_l[t * 256 + i]);
    float bv = xp[t * 64 + 8 + n];
    float dA = __expf(dtv * A);
    P *= dA;
    S = fmaf(S, dA, dtv * bv * hsv);
  }
  int chain = b * 4096 + blockIdx.y * 256 + threadIdx.x;
  Pb[c * 32768 + chain] = P;
  Sb[c * 32768 + chain] = S;
}

// ---------------- phase C: combine prefix + replay, emit y (bf16 hi/lo) ----------------
__global__ __launch_bounds__(256) void scanC_kernel(const float* __restrict__ dtb,
                                                    const bf16* __restrict__ hs_h,
                                                    const bf16* __restrict__ hs_l,
                                                    const float* __restrict__ xp,
                                                    const float* __restrict__ A_log,
                                                    const float* __restrict__ Dp,
                                                    const float* __restrict__ gate_f,
                                                    const float* __restrict__ Pb,
                                                    const float* __restrict__ Sb,
                                                    bf16* __restrict__ y_h,
                                                    bf16* __restrict__ y_l) {
  int b = blockIdx.x;
  int i = blockIdx.y * 16 + (threadIdx.x >> 4);
  int n = threadIdx.x & 15;
  int c = blockIdx.z;
  float A = -__expf(A_log[i * 16 + n]);
  float Dv = Dp[i];
  int chain = b * 4096 + blockIdx.y * 256 + threadIdx.x;
  float state = 0.0f;
  for (int cc = 0; cc < c; ++cc)
    state = fmaf(state, Pb[cc * 32768 + chain], Sb[cc * 32768 + chain]);
  int t0 = b * LSEQ + c * 128;
  for (int l = 0; l < 128; ++l) {
    size_t t = t0 + l;
    float dtv = dtb[t * 256 + i];
    float hsv = __bfloat162float(hs_h[t * 256 + i]) + __bfloat162float(hs_l[t * 256 + i]);
    float bv = xp[t * 64 + 8 + n];
    float cv = xp[t * 64 + 24 + n];
    float dA = __expf(dtv * A);
    state = fmaf(state, dA, dtv * bv * hsv);
    float contrib = state * cv;
    contrib += __shfl_xor(contrib, 1, 16);
    contrib += __shfl_xor(contrib, 2, 16);
    contrib += __shfl_xor(contrib, 4, 16);
    contrib += __shfl_xor(contrib, 8, 16);
    if (n == 0) {
      float g = gate_f[t * 256 + i];
      float val = (contrib + hsv * Dv) * g;
      bf16 hh, ll;
      split_bf16(val, hh, ll);
      y_h[t * 256 + i] = hh;
      y_l[t * 256 + i] = ll;
    }
  }
}

extern "C" void kernel_launch(void* const* d_in, const int* in_sizes, int n_in,
                              void* d_out, int out_size, void* d_ws, size_t ws_size,
                              hipStream_t stream) {
  const int* x           = (const int*)d_in[0];
  const float* embed     = (const float*)d_in[1];
  const float* in_proj_w = (const float*)d_in[2];
  const float* conv_w    = (const float*)d_in[3];
  const float* conv_b    = (const float*)d_in[4];
  const float* x_proj_w  = (const float*)d_in[5];
  const float* dt_proj_w = (const float*)d_in[6];
  const float* dt_proj_b = (const float*)d_in[7];
  const float* A_log     = (const float*)d_in[8];
  const float* Dp        = (const float*)d_in[9];
  const float* out_proj_w= (const float*)d_in[10];
  const float* norm_w    = (const float*)d_in[11];
  const float* norm_f_w  = (const float*)d_in[12];
  const float* head_w    = (const float*)d_in[13];
  const float* head_b    = (const float*)d_in[14];

  float* out = (float*)d_out;
  float* ws  = (float*)d_ws;

  // ---- d_out scratch map (f32 word offsets; budget 33,554,432) ----
  float* hzx     = out;                          //  4,194,304 (T*256 f32)
  float* gate_f  = out + 4194304;                //  4,194,304 (T*256 f32)
  bf16*  hs_h    = (bf16*)(out + 8388608);       //  2,097,152 w
  bf16*  hs_l    = (bf16*)(out + 10485760);      //  2,097,152 w
  float* dtb     = out + 12582912;               //  4,194,304 (T*256 f32)
  float* xp      = out + 16777216;               //  1,048,576 (T*64 f32)
  bf16*  y_h     = (bf16*)(out + 17825792);      //  2,097,152 w
  bf16*  y_l     = (bf16*)(out + 19922944);      //  2,097,152 w
  float* h       = out + 22020096;               //  2,097,152 (T*128 residual)
  bf16*  w_in_h  = (bf16*)(out + 24117248);      //  1,048,576 w
  bf16*  w_in_l  = (bf16*)(out + 25165824);      //  1,048,576 w
  bf16*  w_x_h   = (bf16*)(out + 26214400);      //    262,144 w (padded 64 rows)
  bf16*  w_x_l   = (bf16*)(out + 26476544);
  bf16*  w_out_h = (bf16*)(out + 26738688);      //    524,288 w
  bf16*  w_out_l = (bf16*)(out + 27262976);
  float* Pb      = out + 27787264;               //    524,288 (16*32768)
  float* Sb      = out + 28311552;               // ends 28,835,840

  // ---- ws scratch (~9 MB) — live through the head GEMM ----
  bf16* hn_h     = (bf16*)ws;                    // T*128 bf16
  bf16* hn_l     = (bf16*)(ws + 1048576);
  bf16* w_head_h = (bf16*)(ws + 2097152);        // 2048*128 bf16
  bf16* w_head_l = (bf16*)(ws + 2228224);

  cast_split_kernel<<<8192, 256, 0, stream>>>(in_proj_w, w_in_h, w_in_l, 2097152);
  cast_xproj_kernel<<<2048, 256, 0, stream>>>(x_proj_w, w_x_h, w_x_l);
  cast_split_kernel<<<4096, 256, 0, stream>>>(out_proj_w, w_out_h, w_out_l, 1048576);
  cast_split_kernel<<<1024, 256, 0, stream>>>(head_w, w_head_h, w_head_l, 262144);

  embed_kernel<<<8192, 256, 0, stream>>>(x, embed, h);

  for (int l = 0; l < 32; ++l) {
    rmsnorm_split_kernel<<<4096, 256, 0, stream>>>(h, norm_w + l * 128, hn_h, hn_l);
    inproj_kernel<<<dim3(128, 4), 256, 0, stream>>>(
        hn_h, hn_l, w_in_h + (size_t)l * 512 * 128, w_in_l + (size_t)l * 512 * 128,
        hzx, gate_f);
    conv_silu_kernel<<<4096, 256, 0, stream>>>(hzx, conv_w + l * 1024, conv_b + l * 256,
                                               hs_h, hs_l);
    xproj_dt_kernel<<<512, 256, 0, stream>>>(
        hs_h, hs_l, w_x_h + (size_t)l * 64 * 256, w_x_l + (size_t)l * 64 * 256,
        dt_proj_w + l * 2048, dt_proj_b + l * 256, xp, dtb);
    scanA_kernel<<<dim3(8, 16, 15), 256, 0, stream>>>(
        dtb, hs_h, hs_l, xp, A_log + l * 4096, Pb, Sb);
    scanC_kernel<<<dim3(8, 16, 16), 256, 0, stream>>>(
        dtb, hs_h, hs_l, xp, A_log + l * 4096, Dp + l * 256, gate_f, Pb, Sb, y_h, y_l);
    mfma_gemm<32, 128, 2, 2, 1><<<dim3(512, 1), 256, 0, stream>>>(
        y_h, y_l, w_out_h + (size_t)l * 128 * 256, w_out_l + (size_t)l * 128 * 256,
        h, nullptr, 128, 256);
  }

  rmsnorm_split_kernel<<<4096, 256, 0, stream>>>(h, norm_f_w, hn_h, hn_l);
  mfma_gemm<128, 128, 2, 2, 2><<<dim3(128, 16), 256, 0, stream>>>(
      hn_h, hn_l, w_head_h, w_head_l, out, head_b, 2048, 128);
}

// Round 7
// 4725.065 us; speedup vs baseline: 11.3298x; 1.4334x over previous
//
#include <hip/hip_runtime.h>
#include <hip/hip_bf16.h>

#define LSEQ 2048
#define NCH 32          // chunks per sequence
#define CHL 64          // chunk length (NCH*CHL == LSEQ)

typedef __attribute__((ext_vector_type(8))) short bf16x8;
typedef __attribute__((ext_vector_type(4))) float f32x4;
typedef __hip_bfloat16 bf16;

__device__ __forceinline__ void gload_lds16(const void* g, void* l) {
  __builtin_amdgcn_global_load_lds(
      (const __attribute__((address_space(1))) void*)g,
      (__attribute__((address_space(3))) void*)l, 16, 0, 0);
}

__device__ __forceinline__ void split_bf16(float v, bf16& h, bf16& l) {
  h = __float2bfloat16(v);
  l = __float2bfloat16(v - __bfloat162float(h));
}

// ---------------- embed ----------------
__global__ __launch_bounds__(256) void embed_kernel(const int* __restrict__ x,
                                                    const float* __restrict__ emb,
                                                    float* __restrict__ h) {
  int idx = blockIdx.x * 256 + threadIdx.x;   // T*128
  int t = idx >> 7;
  int d = idx & 127;
  h[idx] = emb[(size_t)x[t] * 128 + d];
}

// ---------------- weight casts (hi/lo split) ----------------
__global__ __launch_bounds__(256) void cast_split_kernel(const float* __restrict__ src,
                                                         bf16* __restrict__ hi,
                                                         bf16* __restrict__ lo, int n) {
  int i = blockIdx.x * 256 + threadIdx.x;
  if (i < n) { bf16 h, l; split_bf16(src[i], h, l); hi[i] = h; lo[i] = l; }
}

// x_proj: src [32][40][256] -> dst [32][64][256], rows 40..63 zero
__global__ __launch_bounds__(256) void cast_xproj_kernel(const float* __restrict__ src,
                                                         bf16* __restrict__ hi,
                                                         bf16* __restrict__ lo) {
  int i = blockIdx.x * 256 + threadIdx.x;   // 32*64*256
  int k = i & 255, n = (i >> 8) & 63, l = i >> 14;
  float v = (n < 40) ? src[((size_t)l * 40 + n) * 256 + k] : 0.f;
  bf16 h, lw; split_bf16(v, h, lw);
  hi[i] = h; lo[i] = lw;
}

// ---------------- rmsnorm -> bf16 hi/lo ----------------
__global__ __launch_bounds__(256) void rmsnorm_split_kernel(const float* __restrict__ hin,
                                                            const float* __restrict__ w,
                                                            bf16* __restrict__ hout_h,
                                                            bf16* __restrict__ hout_l) {
  int row = blockIdx.x * 4 + (threadIdx.x >> 6);
  int lane = threadIdx.x & 63;
  float2 v = *(const float2*)&hin[(size_t)row * 128 + lane * 2];
  float ss = v.x * v.x + v.y * v.y;
  #pragma unroll
  for (int m = 1; m < 64; m <<= 1) ss += __shfl_xor(ss, m);
  float rstd = rsqrtf(ss * (1.0f / 128.0f) + 1e-5f);
  float2 wv = *(const float2*)&w[lane * 2];
  float o0 = v.x * rstd * wv.x, o1 = v.y * rstd * wv.y;
  __hip_bfloat162 ph, pl;
  bf16 hh, ll;
  split_bf16(o0, hh, ll); ph.x = hh; pl.x = ll;
  split_bf16(o1, hh, ll); ph.y = hh; pl.y = ll;
  *(__hip_bfloat162*)&hout_h[(size_t)row * 128 + lane * 2] = ph;
  *(__hip_bfloat162*)&hout_l[(size_t)row * 128 + lane * 2] = pl;
}

// ================= generic split-bf16 MFMA GEMM =================
// EPI 1: C += (residual)   EPI 2: C = val + bias
template <int BM, int BN, int WR, int WC, int EPI>
__global__ __launch_bounds__(256) void mfma_gemm(const bf16* __restrict__ AH,
                                                 const bf16* __restrict__ AL,
                                                 const bf16* __restrict__ WH,
                                                 const bf16* __restrict__ WL,
                                                 float* __restrict__ C,
                                                 const float* __restrict__ bias,
                                                 int Nc, int Kc) {
  constexpr int WTM = BM / WR, WTN = BN / WC;
  constexpr int U = WTM / 16, V = WTN / 16;
  __shared__ bf16 AsH[BM * 64];
  __shared__ bf16 AsL[BM * 64];
  __shared__ bf16 BsH[BN * 64];
  __shared__ bf16 BsL[BN * 64];
  int tid = threadIdx.x;
  int lane = tid & 63, wid = tid >> 6;
  int wr = wid / WC, wc = wid % WC;
  int row0 = blockIdx.x * BM, col0 = blockIdx.y * BN;
  int l15 = lane & 15, l4 = lane >> 4;
  f32x4 acc[U][V] = {};
  for (int k0 = 0; k0 < Kc; k0 += 64) {
    __syncthreads();
    #pragma unroll
    for (int it = 0; it < BM / 32; ++it) {
      int chunk = it * 256 + tid;
      int r = chunk >> 3;
      int clog = (chunk & 7) ^ (r & 7);
      size_t goff = (size_t)(row0 + r) * Kc + k0 + clog * 8;
      gload_lds16(AH + goff, &AsH[chunk * 8]);
      gload_lds16(AL + goff, &AsL[chunk * 8]);
    }
    #pragma unroll
    for (int it = 0; it < BN / 32; ++it) {
      int chunk = it * 256 + tid;
      int r = chunk >> 3;
      int clog = (chunk & 7) ^ (r & 7);
      size_t goff = (size_t)(col0 + r) * Kc + k0 + clog * 8;
      gload_lds16(WH + goff, &BsH[chunk * 8]);
      gload_lds16(WL + goff, &BsL[chunk * 8]);
    }
    __syncthreads();
    #pragma unroll
    for (int kk = 0; kk < 2; ++kk) {
      bf16x8 afh[U], afl[U], bfh[V], bfl[V];
      #pragma unroll
      for (int u = 0; u < U; ++u) {
        int r = wr * WTM + u * 16 + l15;
        int csw = (kk * 4 + l4) ^ (r & 7);
        afh[u] = *(const bf16x8*)&AsH[r * 64 + csw * 8];
        afl[u] = *(const bf16x8*)&AsL[r * 64 + csw * 8];
      }
      #pragma unroll
      for (int v = 0; v < V; ++v) {
        int r = wc * WTN + v * 16 + l15;
        int csw = (kk * 4 + l4) ^ (r & 7);
        bfh[v] = *(const bf16x8*)&BsH[r * 64 + csw * 8];
        bfl[v] = *(const bf16x8*)&BsL[r * 64 + csw * 8];
      }
      #pragma unroll
      for (int u = 0; u < U; ++u)
        #pragma unroll
        for (int v = 0; v < V; ++v) {
          acc[u][v] = __builtin_amdgcn_mfma_f32_16x16x32_bf16(afh[u], bfh[v], acc[u][v], 0, 0, 0);
          acc[u][v] = __builtin_amdgcn_mfma_f32_16x16x32_bf16(afl[u], bfh[v], acc[u][v], 0, 0, 0);
          acc[u][v] = __builtin_amdgcn_mfma_f32_16x16x32_bf16(afh[u], bfl[v], acc[u][v], 0, 0, 0);
        }
    }
  }
  #pragma unroll
  for (int u = 0; u < U; ++u) {
    int rbase = row0 + wr * WTM + u * 16 + l4 * 4;
    #pragma unroll
    for (int v = 0; v < V; ++v) {
      int col = col0 + wc * WTN + v * 16 + l15;
      #pragma unroll
      for (int q = 0; q < 4; ++q) {
        size_t off = (size_t)(rbase + q) * Nc + col;
        float val = acc[u][v][q];
        if (EPI == 1) val += C[off];
        if (EPI == 2) val += bias[col];
        C[off] = val;
      }
    }
  }
}

// ================= in_proj: GEMM (128x128, K=128) writing hzx(f32) / silu(gate)(f32) =================
__global__ __launch_bounds__(256) void inproj_kernel(const bf16* __restrict__ AH,
                                                     const bf16* __restrict__ AL,
                                                     const bf16* __restrict__ WH,
                                                     const bf16* __restrict__ WL,
                                                     float* __restrict__ hzx,
                                                     float* __restrict__ gate_f) {
  constexpr int BM = 128, BN = 128;
  __shared__ bf16 AsH[BM * 64];
  __shared__ bf16 AsL[BM * 64];
  __shared__ bf16 BsH[BN * 64];
  __shared__ bf16 BsL[BN * 64];
  int tid = threadIdx.x;
  int lane = tid & 63, wid = tid >> 6;
  int wr = wid >> 1, wc = wid & 1;
  int row0 = blockIdx.x * BM, col0 = blockIdx.y * BN;
  int l15 = lane & 15, l4 = lane >> 4;
  f32x4 acc[4][4] = {};
  for (int k0 = 0; k0 < 128; k0 += 64) {
    __syncthreads();
    #pragma unroll
    for (int it = 0; it < 4; ++it) {
      int chunk = it * 256 + tid;
      int r = chunk >> 3;
      int clog = (chunk & 7) ^ (r & 7);
      size_t goff = (size_t)(row0 + r) * 128 + k0 + clog * 8;
      gload_lds16(AH + goff, &AsH[chunk * 8]);
      gload_lds16(AL + goff, &AsL[chunk * 8]);
      size_t woff = (size_t)(col0 + r) * 128 + k0 + clog * 8;
      gload_lds16(WH + woff, &BsH[chunk * 8]);
      gload_lds16(WL + woff, &BsL[chunk * 8]);
    }
    __syncthreads();
    #pragma unroll
    for (int kk = 0; kk < 2; ++kk) {
      bf16x8 afh[4], afl[4], bfh[4], bfl[4];
      #pragma unroll
      for (int u = 0; u < 4; ++u) {
        int r = wr * 64 + u * 16 + l15;
        int csw = (kk * 4 + l4) ^ (r & 7);
        afh[u] = *(const bf16x8*)&AsH[r * 64 + csw * 8];
        afl[u] = *(const bf16x8*)&AsL[r * 64 + csw * 8];
      }
      #pragma unroll
      for (int v = 0; v < 4; ++v) {
        int r = wc * 64 + v * 16 + l15;
        int csw = (kk * 4 + l4) ^ (r & 7);
        bfh[v] = *(const bf16x8*)&BsH[r * 64 + csw * 8];
        bfl[v] = *(const bf16x8*)&BsL[r * 64 + csw * 8];
      }
      #pragma unroll
      for (int u = 0; u < 4; ++u)
        #pragma unroll
        for (int v = 0; v < 4; ++v) {
          acc[u][v] = __builtin_amdgcn_mfma_f32_16x16x32_bf16(afh[u], bfh[v], acc[u][v], 0, 0, 0);
          acc[u][v] = __builtin_amdgcn_mfma_f32_16x16x32_bf16(afl[u], bfh[v], acc[u][v], 0, 0, 0);
          acc[u][v] = __builtin_amdgcn_mfma_f32_16x16x32_bf16(afh[u], bfl[v], acc[u][v], 0, 0, 0);
        }
    }
  }
  bool isgate = (col0 >= 256);
  #pragma unroll
  for (int u = 0; u < 4; ++u) {
    int rbase = row0 + wr * 64 + u * 16 + l4 * 4;
    #pragma unroll
    for (int v = 0; v < 4; ++v) {
      int col = col0 + wc * 64 + v * 16 + l15;
      #pragma unroll
      for (int q = 0; q < 4; ++q) {
        float val = acc[u][v][q];
        if (!isgate) {
          hzx[(size_t)(rbase + q) * 256 + col] = val;
        } else {
          float s = val / (1.0f + __expf(-val));
          gate_f[(size_t)(rbase + q) * 256 + (col - 256)] = s;
        }
      }
    }
  }
}

// ================= x_proj (32x64, K=256) + fused dt_proj/softplus =================
__global__ __launch_bounds__(256) void xproj_dt_kernel(const bf16* __restrict__ AH,
                                                       const bf16* __restrict__ AL,
                                                       const bf16* __restrict__ WH,
                                                       const bf16* __restrict__ WL,
                                                       const float* __restrict__ Wdt,
                                                       const float* __restrict__ bdt,
                                                       float* __restrict__ xp,
                                                       float* __restrict__ dtb) {
  constexpr int BM = 32, BN = 64;
  __shared__ bf16 AsH[BM * 64];
  __shared__ bf16 AsL[BM * 64];
  __shared__ bf16 BsH[BN * 64];
  __shared__ bf16 BsL[BN * 64];
  __shared__ float xq[32][8];
  int tid = threadIdx.x;
  int lane = tid & 63, wid = tid >> 6;
  int wr = wid >> 1, wc = wid & 1;   // wave tile 16x32
  int row0 = blockIdx.x * BM;
  int l15 = lane & 15, l4 = lane >> 4;
  f32x4 acc[1][2] = {};
  for (int k0 = 0; k0 < 256; k0 += 64) {
    __syncthreads();
    {
      int chunk = tid;                    // 256 chunks = BM*8
      int r = chunk >> 3;
      int clog = (chunk & 7) ^ (r & 7);
      size_t goff = (size_t)(row0 + r) * 256 + k0 + clog * 8;
      gload_lds16(AH + goff, &AsH[chunk * 8]);
      gload_lds16(AL + goff, &AsL[chunk * 8]);
    }
    #pragma unroll
    for (int it = 0; it < 2; ++it) {
      int chunk = it * 256 + tid;
      int r = chunk >> 3;
      int clog = (chunk & 7) ^ (r & 7);
      size_t goff = (size_t)r * 256 + k0 + clog * 8;
      gload_lds16(WH + goff, &BsH[chunk * 8]);
      gload_lds16(WL + goff, &BsL[chunk * 8]);
    }
    __syncthreads();
    #pragma unroll
    for (int kk = 0; kk < 2; ++kk) {
      bf16x8 afh, afl, bfh[2], bfl[2];
      {
        int r = wr * 16 + l15;
        int csw = (kk * 4 + l4) ^ (r & 7);
        afh = *(const bf16x8*)&AsH[r * 64 + csw * 8];
        afl = *(const bf16x8*)&AsL[r * 64 + csw * 8];
      }
      #pragma unroll
      for (int v = 0; v < 2; ++v) {
        int r = wc * 32 + v * 16 + l15;
        int csw = (kk * 4 + l4) ^ (r & 7);
        bfh[v] = *(const bf16x8*)&BsH[r * 64 + csw * 8];
        bfl[v] = *(const bf16x8*)&BsL[r * 64 + csw * 8];
      }
      #pragma unroll
      for (int v = 0; v < 2; ++v) {
        acc[0][v] = __builtin_amdgcn_mfma_f32_16x16x32_bf16(afh, bfh[v], acc[0][v], 0, 0, 0);
        acc[0][v] = __builtin_amdgcn_mfma_f32_16x16x32_bf16(afl, bfh[v], acc[0][v], 0, 0, 0);
        acc[0][v] = __builtin_amdgcn_mfma_f32_16x16x32_bf16(afh, bfl[v], acc[0][v], 0, 0, 0);
      }
    }
  }
  // epilogue: write xp; stash cols 0..7 into LDS
  {
    int rbase = wr * 16 + l4 * 4;
    #pragma unroll
    for (int v = 0; v < 2; ++v) {
      int col = wc * 32 + v * 16 + l15;
      #pragma unroll
      for (int q = 0; q < 4; ++q) {
        float val = acc[0][v][q];
        xp[(size_t)(row0 + rbase + q) * 64 + col] = val;
        if (col < 8) xq[rbase + q][col] = val;
      }
    }
  }
  __syncthreads();
  // dt phase: thread i computes dt for all 32 tokens of this tile
  {
    int i = tid;
    const float* wr8 = Wdt + i * 8;
    float w0 = wr8[0], w1 = wr8[1], w2 = wr8[2], w3 = wr8[3];
    float w4 = wr8[4], w5 = wr8[5], w6 = wr8[6], w7 = wr8[7];
    float bv = bdt[i];
    #pragma unroll 4
    for (int tt = 0; tt < 32; ++tt) {
      const float* q = xq[tt];
      float s = bv;
      s = fmaf(q[0], w0, s); s = fmaf(q[1], w1, s);
      s = fmaf(q[2], w2, s); s = fmaf(q[3], w3, s);
      s = fmaf(q[4], w4, s); s = fmaf(q[5], w5, s);
      s = fmaf(q[6], w6, s); s = fmaf(q[7], w7, s);
      float sp = (s > 20.0f) ? s : log1pf(__expf(s));
      dtb[(size_t)(row0 + tt) * 256 + i] = sp;
    }
  }
}

// ---------------- causal depthwise conv (K=4) + bias + silu -> bf16 hi/lo ----------------
__global__ __launch_bounds__(256) void conv_silu_kernel(const float* __restrict__ hzx,
                                                        const float* __restrict__ cw,
                                                        const float* __restrict__ cb,
                                                        bf16* __restrict__ hs_h,
                                                        bf16* __restrict__ hs_l) {
  int idx = blockIdx.x * 256 + threadIdx.x;   // T*64
  int c4 = idx & 63;
  int t = idx >> 6;
  int l = t & (LSEQ - 1);
  float w[4][4];
  #pragma unroll
  for (int j = 0; j < 4; ++j) {
    float4 wv = *(const float4*)&cw[(c4 * 4 + j) * 4];
    w[j][0] = wv.x; w[j][1] = wv.y; w[j][2] = wv.z; w[j][3] = wv.w;
  }
  float4 acc = *(const float4*)&cb[c4 * 4];
  #pragma unroll
  for (int k = 0; k < 4; ++k) {
    int ll = l + k - 3;
    if (ll >= 0) {
      float4 v = *(const float4*)&hzx[(size_t)(t + k - 3) * 256 + c4 * 4];
      acc.x = fmaf(v.x, w[0][k], acc.x);
      acc.y = fmaf(v.y, w[1][k], acc.y);
      acc.z = fmaf(v.z, w[2][k], acc.z);
      acc.w = fmaf(v.w, w[3][k], acc.w);
    }
  }
  acc.x = acc.x / (1.0f + __expf(-acc.x));
  acc.y = acc.y / (1.0f + __expf(-acc.y));
  acc.z = acc.z / (1.0f + __expf(-acc.z));
  acc.w = acc.w / (1.0f + __expf(-acc.w));
  bf16 hh, ll2;
  __hip_bfloat162 h01, h23, l01, l23;
  split_bf16(acc.x, hh, ll2); h01.x = hh; l01.x = ll2;
  split_bf16(acc.y, hh, ll2); h01.y = hh; l01.y = ll2;
  split_bf16(acc.z, hh, ll2); h23.x = hh; l23.x = ll2;
  split_bf16(acc.w, hh, ll2); h23.y = hh; l23.y = ll2;
  *(__hip_bfloat162*)&hs_h[(size_t)t * 256 + c4 * 4] = h01;
  *(__hip_bfloat162*)&hs_h[(size_t)t * 256 + c4 * 4 + 2] = h23;
  *(__hip_bfloat162*)&hs_l[(size_t)t * 256 + c4 * 4] = l01;
  *(__hip_bfloat162*)&hs_l[(size_t)t * 256 + c4 * 4 + 2] = l23;
}

// ================= chunked scan, lane-per-channel (16 states in registers) =================
// phase A: per-chunk products/sums.  grid (8, NCH), block 256 (= I channels)
__global__ __launch_bounds__(256) void scanA_kernel(const float* __restrict__ dtb,
                                                    const bf16* __restrict__ hs_h,
                                                    const bf16* __restrict__ hs_l,
                                                    const float* __restrict__ xp,
                                                    const float* __restrict__ A_log,
                                                    float* __restrict__ Pb,
                                                    float* __restrict__ Sb) {
  int b = blockIdx.x, c = blockIdx.y, i = threadIdx.x;
  float A[16];
  {
    const float4* ap = (const float4*)&A_log[i * 16];
    #pragma unroll
    for (int q = 0; q < 4; ++q) {
      float4 a = ap[q];
      A[q * 4 + 0] = -__expf(a.x); A[q * 4 + 1] = -__expf(a.y);
      A[q * 4 + 2] = -__expf(a.z); A[q * 4 + 3] = -__expf(a.w);
    }
  }
  float P[16], S[16];
  #pragma unroll
  for (int n = 0; n < 16; ++n) { P[n] = 1.0f; S[n] = 0.0f; }
  int t0 = b * LSEQ + c * CHL;
  for (int l = 0; l < CHL; ++l) {
    size_t t = t0 + l;
    float dtv = dtb[t * 256 + i];
    float hsv = __bfloat162float(hs_h[t * 256 + i]) + __bfloat162float(hs_l[t * 256 + i]);
    float dh = dtv * hsv;
    float Bv[16];
    #pragma unroll
    for (int q = 0; q < 4; ++q) {
      float4 bv = *(const float4*)&xp[t * 64 + 8 + q * 4];
      Bv[q * 4 + 0] = bv.x; Bv[q * 4 + 1] = bv.y; Bv[q * 4 + 2] = bv.z; Bv[q * 4 + 3] = bv.w;
    }
    #pragma unroll
    for (int n = 0; n < 16; ++n) {
      float e = __expf(dtv * A[n]);
      P[n] *= e;
      S[n] = fmaf(S[n], e, dh * Bv[n]);
    }
  }
  size_t base = ((size_t)(b * NCH + c) << 12) + i * 16;
  #pragma unroll
  for (int q = 0; q < 4; ++q) {
    *(float4*)&Pb[base + q * 4] = make_float4(P[q * 4], P[q * 4 + 1], P[q * 4 + 2], P[q * 4 + 3]);
    *(float4*)&Sb[base + q * 4] = make_float4(S[q * 4], S[q * 4 + 1], S[q * 4 + 2], S[q * 4 + 3]);
  }
}

// phase B: sequential prefix over chunks -> initial states. 32768 threads.
__global__ __launch_bounds__(256) void scanB_kernel(const float* __restrict__ Pb,
                                                    const float* __restrict__ Sb,
                                                    float* __restrict__ Ib) {
  int g = blockIdx.x * 256 + threadIdx.x;   // b*4096 + i*16 + n
  int b = g >> 12, rem = g & 4095;
  float s = 0.0f;
  #pragma unroll
  for (int cc = 0; cc < NCH; ++cc) {
    size_t off = ((size_t)(b * NCH + cc) << 12) + rem;
    Ib[off] = s;
    s = fmaf(s, Pb[off], Sb[off]);
  }
}

// phase C: replay with initial state, emit y = (sum_n state*C + hs*D) * gate
__global__ __launch_bounds__(256) void scanC_kernel(const float* __restrict__ dtb,
                                                    const bf16* __restrict__ hs_h,
                                                    const bf16* __restrict__ hs_l,
                                                    const float* __restrict__ xp,
                                                    const float* __restrict__ A_log,
                                                    const float* __restrict__ Dp,
                                                    const float* __restrict__ gate_f,
                                                    const float* __restrict__ Ib,
                                                    bf16* __restrict__ y_h,
                                                    bf16* __restrict__ y_l) {
  int b = blockIdx.x, c = blockIdx.y, i = threadIdx.x;
  float A[16];
  {
    const float4* ap = (const float4*)&A_log[i * 16];
    #pragma unroll
    for (int q = 0; q < 4; ++q) {
      float4 a = ap[q];
      A[q * 4 + 0] = -__expf(a.x); A[q * 4 + 1] = -__expf(a.y);
      A[q * 4 + 2] = -__expf(a.z); A[q * 4 + 3] = -__expf(a.w);
    }
  }
  float st[16];
  {
    size_t base = ((size_t)(b * NCH + c) << 12) + i * 16;
    #pragma unroll
    for (int q = 0; q < 4; ++q) {
      float4 s4 = *(const float4*)&Ib[base + q * 4];
      st[q * 4 + 0] = s4.x; st[q * 4 + 1] = s4.y; st[q * 4 + 2] = s4.z; st[q * 4 + 3] = s4.w;
    }
  }
  float Dv = Dp[i];
  int t0 = b * LSEQ + c * CHL;
  for (int l = 0; l < CHL; ++l) {
    size_t t = t0 + l;
    float dtv = dtb[t * 256 + i];
    float hsv = __bfloat162float(hs_h[t * 256 + i]) + __bfloat162float(hs_l[t * 256 + i]);
    float dh = dtv * hsv;
    float Bv[16], Cv[16];
    #pragma unroll
    for (int q = 0; q < 4; ++q) {
      float4 bv = *(const float4*)&xp[t * 64 + 8 + q * 4];
      Bv[q * 4 + 0] = bv.x; Bv[q * 4 + 1] = bv.y; Bv[q * 4 + 2] = bv.z; Bv[q * 4 + 3] = bv.w;
      float4 cv = *(const float4*)&xp[t * 64 + 24 + q * 4];
      Cv[q * 4 + 0] = cv.x; Cv[q * 4 + 1] = cv.y; Cv[q * 4 + 2] = cv.z; Cv[q * 4 + 3] = cv.w;
    }
    float y0 = 0.f, y1 = 0.f, y2 = 0.f, y3 = 0.f;
    #pragma unroll
    for (int q = 0; q < 4; ++q) {
      float e0 = __expf(dtv * A[q * 4 + 0]);
      float e1 = __expf(dtv * A[q * 4 + 1]);
      float e2 = __expf(dtv * A[q * 4 + 2]);
      float e3 = __expf(dtv * A[q * 4 + 3]);
      st[q * 4 + 0] = fmaf(st[q * 4 + 0], e0, dh * Bv[q * 4 + 0]);
      st[q * 4 + 1] = fmaf(st[q * 4 + 1], e1, dh * Bv[q * 4 + 1]);
      st[q * 4 + 2] = fmaf(st[q * 4 + 2], e2, dh * Bv[q * 4 + 2]);
      st[q * 4 + 3] = fmaf(st[q * 4 + 3], e3, dh * Bv[q * 4 + 3]);
      y0 = fmaf(st[q * 4 + 0], Cv[q * 4 + 0], y0);
      y1 = fmaf(st[q * 4 + 1], Cv[q * 4 + 1], y1);
      y2 = fmaf(st[q * 4 + 2], Cv[q * 4 + 2], y2);
      y3 = fmaf(st[q * 4 + 3], Cv[q * 4 + 3], y3);
    }
    float y = ((y0 + y1) + (y2 + y3)) + hsv * Dv;
    float g = gate_f[t * 256 + i];
    float val = y * g;
    bf16 hh, ll;
    split_bf16(val, hh, ll);
    y_h[t * 256 + i] = hh;
    y_l[t * 256 + i] = ll;
  }
}

extern "C" void kernel_launch(void* const* d_in, const int* in_sizes, int n_in,
                              void* d_out, int out_size, void* d_ws, size_t ws_size,
                              hipStream_t stream) {
  const int* x           = (const int*)d_in[0];
  const float* embed     = (const float*)d_in[1];
  const float* in_proj_w = (const float*)d_in[2];
  const float* conv_w    = (const float*)d_in[3];
  const float* conv_b    = (const float*)d_in[4];
  const float* x_proj_w  = (const float*)d_in[5];
  const float* dt_proj_w = (const float*)d_in[6];
  const float* dt_proj_b = (const float*)d_in[7];
  const float* A_log     = (const float*)d_in[8];
  const float* Dp        = (const float*)d_in[9];
  const float* out_proj_w= (const float*)d_in[10];
  const float* norm_w    = (const float*)d_in[11];
  const float* norm_f_w  = (const float*)d_in[12];
  const float* head_w    = (const float*)d_in[13];
  const float* head_b    = (const float*)d_in[14];

  float* out = (float*)d_out;
  float* ws  = (float*)d_ws;

  // ---- d_out scratch map (f32 word offsets; budget 33,554,432) ----
  float* hzx     = out;                          //  4,194,304 (T*256 f32)
  float* gate_f  = out + 4194304;                //  4,194,304 (T*256 f32)
  bf16*  hs_h    = (bf16*)(out + 8388608);       //  2,097,152 w
  bf16*  hs_l    = (bf16*)(out + 10485760);      //  2,097,152 w
  float* dtb     = out + 12582912;               //  4,194,304 (T*256 f32)
  float* xp      = out + 16777216;               //  1,048,576 (T*64 f32)
  bf16*  y_h     = (bf16*)(out + 17825792);      //  2,097,152 w
  bf16*  y_l     = (bf16*)(out + 19922944);      //  2,097,152 w
  float* h       = out + 22020096;               //  2,097,152 (T*128 residual)
  bf16*  w_in_h  = (bf16*)(out + 24117248);      //  1,048,576 w
  bf16*  w_in_l  = (bf16*)(out + 25165824);      //  1,048,576 w
  bf16*  w_x_h   = (bf16*)(out + 26214400);      //    262,144 w (padded 64 rows)
  bf16*  w_x_l   = (bf16*)(out + 26476544);
  bf16*  w_out_h = (bf16*)(out + 26738688);      //    524,288 w
  bf16*  w_out_l = (bf16*)(out + 27262976);
  float* Pb      = out + 27787264;               //  1,048,576 (8*NCH*4096)
  float* Sb      = out + 28835840;               //  1,048,576
  float* Ib      = out + 29884416;               //  1,048,576 -> ends 30,932,992

  // ---- ws scratch (~9 MB) — live through the head GEMM ----
  bf16* hn_h     = (bf16*)ws;                    // T*128 bf16
  bf16* hn_l     = (bf16*)(ws + 1048576);
  bf16* w_head_h = (bf16*)(ws + 2097152);        // 2048*128 bf16
  bf16* w_head_l = (bf16*)(ws + 2228224);

  cast_split_kernel<<<8192, 256, 0, stream>>>(in_proj_w, w_in_h, w_in_l, 2097152);
  cast_xproj_kernel<<<2048, 256, 0, stream>>>(x_proj_w, w_x_h, w_x_l);
  cast_split_kernel<<<4096, 256, 0, stream>>>(out_proj_w, w_out_h, w_out_l, 1048576);
  cast_split_kernel<<<1024, 256, 0, stream>>>(head_w, w_head_h, w_head_l, 262144);

  embed_kernel<<<8192, 256, 0, stream>>>(x, embed, h);

  for (int l = 0; l < 32; ++l) {
    rmsnorm_split_kernel<<<4096, 256, 0, stream>>>(h, norm_w + l * 128, hn_h, hn_l);
    inproj_kernel<<<dim3(128, 4), 256, 0, stream>>>(
        hn_h, hn_l, w_in_h + (size_t)l * 512 * 128, w_in_l + (size_t)l * 512 * 128,
        hzx, gate_f);
    conv_silu_kernel<<<4096, 256, 0, stream>>>(hzx, conv_w + l * 1024, conv_b + l * 256,
                                               hs_h, hs_l);
    xproj_dt_kernel<<<512, 256, 0, stream>>>(
        hs_h, hs_l, w_x_h + (size_t)l * 64 * 256, w_x_l + (size_t)l * 64 * 256,
        dt_proj_w + l * 2048, dt_proj_b + l * 256, xp, dtb);
    scanA_kernel<<<dim3(8, NCH), 256, 0, stream>>>(
        dtb, hs_h, hs_l, xp, A_log + l * 4096, Pb, Sb);
    scanB_kernel<<<128, 256, 0, stream>>>(Pb, Sb, Ib);
    scanC_kernel<<<dim3(8, NCH), 256, 0, stream>>>(
        dtb, hs_h, hs_l, xp, A_log + l * 4096, Dp + l * 256, gate_f, Ib, y_h, y_l);
    mfma_gemm<32, 128, 2, 2, 1><<<dim3(512, 1), 256, 0, stream>>>(
        y_h, y_l, w_out_h + (size_t)l * 128 * 256, w_out_l + (size_t)l * 128 * 256,
        h, nullptr, 128, 256);
  }

  rmsnorm_split_kernel<<<4096, 256, 0, stream>>>(h, norm_f_w, hn_h, hn_l);
  mfma_gemm<128, 128, 2, 2, 2><<<dim3(128, 16), 256, 0, stream>>>(
      hn_h, hn_l, w_head_h, w_head_l, out, head_b, 2048, 128);
}